// Round 2
// baseline (178.897 us; speedup 1.0000x reference)
//
#include <hip/hip_runtime.h>
#include <math.h>

// Problem constants (match reference)
#define N_ATOMS 768
#define FD 128          // feature width
#define NRBF 32
#define MAXN 64         // per-atom neighbor cap (mean ~26)
#define PPF 32          // fwd: pairs per block (4 pairs x 4 cols per thread)
#define PPBW 16         // bwd: pairs per block (2 pairs x 4 cols per thread)
#define FTILES (N_ATOMS * MAXN / PPF)     // 1536
#define BTILES (N_ATOMS * MAXN / PPBW)    // 3072
#define AST 132         // padded LDS stride for [*][128] tiles (16B-aligned)
#define RST 36          // padded LDS stride for [*][32] rbf tiles
#define KC  16          // weight-chunk rows staged in LDS per GEMM step

constexpr float  CUT2   = 25.0f;
constexpr float  GAMMA_ = 40.96f;            // 1/(5/32)^2
constexpr float  CSTEP  = 5.0f / 31.0f;      // linspace(0,5,32) step
constexpr double KB_D   = 8.617330337217213e-05;
constexpr double KT_D   = 300.0 * KB_D;
constexpr float  KT_F   = (float)KT_D;
constexpr float  TARGET_KE = (float)(0.5 * 2304.0 * KT_D);
constexpr float  Q0_F   = (float)(2.0 * 2304.0 * KT_D * 400.0);  // Q[0]
constexpr float  QI_F   = (float)(2.0 * KT_D * 400.0);           // Q[1..3]

#define DVDT_OFF 0
#define V_OFF    (3 * N_ATOMS)
#define PETA_OFF (6 * N_ATOMS)

// Hard-won rules (18 rounds of counters):
// 1. NO __launch_bounds__ min-wave hints on GEMM kernels — compiler squeezes
//    VGPRs below demand -> scratch spills -> 100s-of-MB symmetric FETCH/WRITE,
//    dur ~ spill/2.5 TB/s (R3/R5/R6/R7/R9/R11).
// 2. Reduce register demand STRUCTURALLY — phase-split through LDS so heavy
//    phases don't overlap (R12 bwd 220->48 VGPR; R16 fwd diet -> 164 us).
// 3. Tile economics differ per kernel: fwd wants PPF=32 (W2 stream amortized),
//    bwd wants PPBW=16 (grid fill; lighter inner loop) (R12/R13).
// 4. NEVER put __threadfence / completion counters on the hot grid — device
//    fence ~ L2 flush per block: R14 bwd 44.6 -> 225 us (also explains R8).
// 5. R17: mbar fused into bwd by REDUNDANT RECOMPUTE per block (dispatch
//    boundary provides the sync; no fences) — kills one dispatch.
// 6. R18 FAILED: per-wave mbar + reg-gef -> 60.5 us (VALUBusy 30->23). The
//    mbar phase is NOT the critical path; reg-gef 4x'd W1 re-reads. Reverted.
// 7. R19 theory: the limiter is 8x intra-block redundant weight streaming
//    (every st-group loads the same W2T/W2 row-block from L2: ~640 MB L2
//    traffic in bwd, ~786 MB in fwd). Fix: stage 16-row weight chunks in LDS
//    once per block; consume via ds_read_b128.

// ---------------------------------------------------------------- prep
__global__ __launch_bounds__(256) void prep_kernel(
    const float* __restrict__ q, const int* __restrict__ z,
    const float* __restrict__ embed, const float* __restrict__ W2,
    const float* __restrict__ W3,
    float* __restrict__ h, float* __restrict__ W2T, float* __restrict__ W3T,
    int* __restrict__ pair_i, int* __restrict__ pair_j,
    float* __restrict__ pair_d, float* __restrict__ pair_dx,
    float* __restrict__ pair_dy, float* __restrict__ pair_dz,
    int* __restrict__ npairs_ctr,
    float* __restrict__ m, float* __restrict__ f_acc)
{
    __shared__ int   nj[MAXN];
    __shared__ float nd[MAXN], ndx[MAXN], ndy[MAXN], ndz[MAXN];
    __shared__ int cnt_s, base_s;
    int i = blockIdx.x, t = threadIdx.x;
    if (t == 0) cnt_s = 0;
    __syncthreads();
    float qx = q[i*3], qy = q[i*3+1], qz = q[i*3+2];
    for (int j = t; j < N_ATOMS; j += 256) {
        if (j == i) continue;
        float dx = qx - q[j*3], dy = qy - q[j*3+1], dz = qz - q[j*3+2];
        float d2 = dx*dx + dy*dy + dz*dz;
        if (d2 < CUT2) {
            int p = atomicAdd(&cnt_s, 1);
            if (p < MAXN) { nj[p] = j; nd[p] = sqrtf(d2);
                            ndx[p] = dx; ndy[p] = dy; ndz[p] = dz; }
        }
    }
    int g = i * 256 + t;                         // 196608 global ids
    if (g < N_ATOMS * FD) { h[g] = embed[z[g >> 7] * FD + (g & 127)]; m[g] = 0.f; }
    int g2 = g - N_ATOMS * FD;
    if (g2 >= 0 && g2 < FD * FD) {
        int r = g2 >> 7, c = g2 & 127;
        W2T[c * FD + r] = W2[g2];
        W3T[c * FD + r] = W3[g2];
    }
    if (g < 3 * N_ATOMS) f_acc[g] = 0.f;
    __syncthreads();
    if (t == 0) base_s = atomicAdd(npairs_ctr, min(cnt_s, MAXN));
    __syncthreads();
    int cnt = min(cnt_s, MAXN), base = base_s;
    if (t < cnt) {
        pair_i[base+t] = i;      pair_j[base+t] = nj[t];
        pair_d[base+t] = nd[t];  pair_dx[base+t] = ndx[t];
        pair_dy[base+t] = ndy[t]; pair_dz[base+t] = ndz[t];
    }
}

// ---------------------------------------------------------------- fwd (PPF=32)
// R16 three-phase register-diet structure + R19 LDS weight-chunk staging.
__global__ __launch_bounds__(256) void fwd_kernel(
    const float* __restrict__ W1, const float* __restrict__ b1,
    const float* __restrict__ W2, const float* __restrict__ b2,
    const float* __restrict__ h,
    const int* __restrict__ pair_i, const int* __restrict__ pair_j,
    const float* __restrict__ pair_d, const int* __restrict__ npairs_ctr,
    float* __restrict__ m)
{
    __shared__ float rbf_s[PPF * RST];    //  4608 B
    __shared__ float a1_s[PPF * AST];     // 16896 B
    __shared__ float filt_s[PPF * AST];   // 16896 B
    __shared__ float w2c_s[KC * FD];      //  8192 B (weight chunk)
    __shared__ int   pis[PPF], pjs[PPF];  //   256 B  (total ~46.8 KB)
    int t = threadIdx.x;
    int base = blockIdx.x * PPF;
    int np = npairs_ctr[0];
    if (base >= np) return;

    if (t < PPF) {
        int p = base + t; bool ok = p < np;
        pis[t] = ok ? pair_i[p] : 0;
        pjs[t] = ok ? pair_j[p] : 0;
    }
    for (int idx = t; idx < PPF * NRBF; idx += 256) {
        int p = idx >> 5, k = idx & 31;
        int gp = base + p;
        float d = (gp < np) ? pair_d[gp] : 1.0f;
        float u = d - CSTEP * (float)k;
        rbf_s[p * RST + k] = __expf(-GAMMA_ * u * u);
    }
    __syncthreads();

    // Phase A: a1[p][c] = relu(b1[c] + rbf[p]@W1[:,c]); thread = (c, 16-pair half)
    {
        int c = t & 127, ph = t >> 7;
        float w1c[NRBF];
#pragma unroll
        for (int k = 0; k < NRBF; k++) w1c[k] = W1[k * FD + c];
        float b1c = b1[c];
        for (int p = ph * 16; p < ph * 16 + 16; p++) {
            float u = b1c;
#pragma unroll
            for (int k4 = 0; k4 < NRBF / 4; k4++) {
                float4 r = *(const float4*)(rbf_s + p * RST + k4 * 4);
                u += r.x*w1c[k4*4] + r.y*w1c[k4*4+1] + r.z*w1c[k4*4+2] + r.w*w1c[k4*4+3];
            }
            a1_s[p * AST + c] = fmaxf(u, 0.f);
        }
    }
    __syncthreads();

    // Phase B: filt[p][c4..] = a1[p] @ W2[:,c4..]  (raw; b2 added in phase C)
    // R19: W2 chunk staged in LDS once per block (was: 8x redundant L2 stream).
    {
        int st = t >> 5, cg = t & 31, c4 = 4 * cg;
        float acc[4][4];
#pragma unroll
        for (int e = 0; e < 4; e++) { acc[e][0]=0; acc[e][1]=0; acc[e][2]=0; acc[e][3]=0; }
        for (int kc = 0; kc < FD; kc += KC) {
            *(float4*)(w2c_s + 4*t)        = *(const float4*)(W2 + kc*FD + 4*t);
            *(float4*)(w2c_s + 4*t + 1024) = *(const float4*)(W2 + kc*FD + 4*t + 1024);
            __syncthreads();
#pragma unroll
            for (int k = 0; k < KC; k += 4) {
                float4 w0 = *(const float4*)(w2c_s + (k+0) * FD + c4);
                float4 w1v= *(const float4*)(w2c_s + (k+1) * FD + c4);
                float4 w2v= *(const float4*)(w2c_s + (k+2) * FD + c4);
                float4 w3v= *(const float4*)(w2c_s + (k+3) * FD + c4);
#pragma unroll
                for (int e = 0; e < 4; e++) {
                    float4 a = *(const float4*)(a1_s + (st*4+e) * AST + kc + k);
                    acc[e][0] += a.x*w0.x + a.y*w1v.x + a.z*w2v.x + a.w*w3v.x;
                    acc[e][1] += a.x*w0.y + a.y*w1v.y + a.z*w2v.y + a.w*w3v.y;
                    acc[e][2] += a.x*w0.z + a.y*w1v.z + a.z*w2v.z + a.w*w3v.z;
                    acc[e][3] += a.x*w0.w + a.y*w1v.w + a.z*w2v.w + a.w*w3v.w;
                }
            }
            __syncthreads();
        }
#pragma unroll
        for (int e = 0; e < 4; e++) {
            float4 fv; fv.x = acc[e][0]; fv.y = acc[e][1];
            fv.z = acc[e][2]; fv.w = acc[e][3];
            *(float4*)(filt_s + (st*4+e) * AST + c4) = fv;
        }
    }
    __syncthreads();

    // Phase C: m[i,c] += (filt[p][c]+b2[c]) * h[j_p][c]; thread = (c, half)
    {
        int c = t & 127, ph = t >> 7;
        float b2c = b2[c];
        float r = 0.f;
        int p0 = ph * 16;
        int cur_i = pis[p0];
        for (int p = p0; p < p0 + 16; p++) {
            int ip = pis[p];
            if (ip != cur_i) {
                atomicAdd(m + cur_i * FD + c, r);
                r = 0.f; cur_i = ip;
            }
            if (base + p < np)
                r += (filt_s[p * AST + c] + b2c) * h[pjs[p] * FD + c];
        }
        atomicAdd(m + cur_i * FD + c, r);
    }
}

// ---------------------------------------------------------------- bwd (PPBW=16)
// R12/R13 register-diet structure + fused in-block mbar recompute (R17) +
// R19 LDS weight-chunk staging in the GEMM (was: 8x redundant L2 stream).
__global__ __launch_bounds__(256) void bwd_kernel(
    const float* __restrict__ W1, const float* __restrict__ b1,
    const float* __restrict__ W2T, const float* __restrict__ h,
    const float* __restrict__ m, const float* __restrict__ W3,
    const float* __restrict__ W3T, const float* __restrict__ wout,
    const int* __restrict__ pair_i, const int* __restrict__ pair_j,
    const float* __restrict__ pair_d, const float* __restrict__ pair_dx,
    const float* __restrict__ pair_dy, const float* __restrict__ pair_dz,
    const int* __restrict__ npairs_ctr, float* __restrict__ f_acc)
{
    __shared__ float rbf_s[PPBW * RST];    //  2304 B
    __shared__ float crbf_s[PPBW * RST];   //  2304 B
    __shared__ float ts[PPBW * AST];       //  8448 B
    __shared__ float gef[PPBW * AST];      //  8448 B
    __shared__ float w2c_s[KC * FD];       //  8192 B (weight chunk)
    __shared__ float mrow[FD], gbrow[FD], mbrow[FD];   // 1536 B
    __shared__ int   pis[PPBW], pjs[PPBW];
    __shared__ int   da_s[PPBW];
    __shared__ int   nda_s;                // total ~31.4 KB -> 5 blocks/CU
    int t = threadIdx.x;
    int base = blockIdx.x * PPBW;
    int np = npairs_ctr[0];
    if (base >= np) return;

    if (t < PPBW) {
        int p = base + t; bool ok = p < np;
        pis[t] = ok ? pair_i[p] : 0;
        pjs[t] = ok ? pair_j[p] : 0;
    }
    for (int idx = t; idx < PPBW * NRBF; idx += 256) {
        int p = idx >> 5, k = idx & 31;
        int gp = base + p;
        float d = (gp < np) ? pair_d[gp] : 1.0f;
        float u = d - CSTEP * (float)k;
        float r = __expf(-GAMMA_ * u * u);
        rbf_s[p * RST + k]  = r;
        crbf_s[p * RST + k] = -2.f * GAMMA_ * u * r;
    }
    __syncthreads();                       // pis/pjs + rbf/crbf ready

    // distinct atom list (runs are contiguous; typically 1-3 entries)
    if (t == 0) {
        int n = 0;
#pragma unroll
        for (int p = 0; p < PPBW; p++) {
            int ip = pis[p];
            bool seen = false;
            for (int k = 0; k < n; k++) if (da_s[k] == ip) { seen = true; break; }
            if (!seen) da_s[n++] = ip;
        }
        nda_s = n;
    }
    __syncthreads();
    int nda = nda_s;

    // per-distinct-atom mbar recompute + ts fill
    for (int k = 0; k < nda; k++) {
        int ia = da_s[k];
        if (t < FD) mrow[t] = m[ia * FD + t];
        __syncthreads();
        if (t < FD) {
            float g3 = 0.f;
#pragma unroll 8
            for (int f = 0; f < FD; f++) g3 += mrow[f] * W3[f * FD + t];
            gbrow[t] = (g3 > 0.f) ? wout[t] : 0.f;
        }
        __syncthreads();
        if (t < FD) {
            float mb = 0.f;
#pragma unroll 8
            for (int f = 0; f < FD; f++) mb += gbrow[f] * W3T[f * FD + t];
            mbrow[t] = mb;
        }
        __syncthreads();
        for (int idx = t; idx < PPBW * 32; idx += 256) {
            int p = idx >> 5, c4g = (idx & 31) * 4;
            if (pis[p] == ia) {
                float4 mb4 = *(const float4*)(mbrow + c4g);
                float4 hj4 = *(const float4*)(h + pjs[p] * FD + c4g);
                float4 tv; tv.x = mb4.x*hj4.x; tv.y = mb4.y*hj4.y;
                tv.z = mb4.z*hj4.z; tv.w = mb4.w*hj4.w;
                *(float4*)(ts + p * AST + c4g) = tv;
            }
        }
        __syncthreads();                   // mrow reused next iteration
    }

    // gef phase: thread = (c, 8-pair half); w1c regs die at phase end
    {
        int c = t & 127, ph = t >> 7;
        float w1c[NRBF];
#pragma unroll
        for (int k = 0; k < NRBF; k++) w1c[k] = W1[k * FD + c];
        float b1c = b1[c];
        for (int p = ph * 8; p < ph * 8 + 8; p++) {
            float u1 = b1c, ef = 0.f;
#pragma unroll
            for (int k4 = 0; k4 < NRBF / 4; k4++) {
                float4 r = *(const float4*)(rbf_s  + p * RST + k4 * 4);
                float4 cd= *(const float4*)(crbf_s + p * RST + k4 * 4);
                u1 += r.x*w1c[k4*4] + r.y*w1c[k4*4+1] + r.z*w1c[k4*4+2] + r.w*w1c[k4*4+3];
                ef += cd.x*w1c[k4*4] + cd.y*w1c[k4*4+1] + cd.z*w1c[k4*4+2] + cd.w*w1c[k4*4+3];
            }
            gef[p * AST + c] = (u1 > 0.f) ? ef : 0.f;
        }
    }
    __syncthreads();

    // GEMM: du1[p][c4..] = ts[p] @ W2T[:,c4..]; fold gef immediately.
    // R19: W2T chunk staged in LDS once per block.
    int st = t >> 5, cg = t & 31, c4 = 4 * cg;
    float acc[2][4];
#pragma unroll
    for (int e = 0; e < 2; e++) { acc[e][0]=0; acc[e][1]=0; acc[e][2]=0; acc[e][3]=0; }
    for (int kc = 0; kc < FD; kc += KC) {
        *(float4*)(w2c_s + 4*t)        = *(const float4*)(W2T + kc*FD + 4*t);
        *(float4*)(w2c_s + 4*t + 1024) = *(const float4*)(W2T + kc*FD + 4*t + 1024);
        __syncthreads();
#pragma unroll
        for (int k = 0; k < KC; k += 4) {
            float4 w0 = *(const float4*)(w2c_s + (k+0) * FD + c4);
            float4 w1v= *(const float4*)(w2c_s + (k+1) * FD + c4);
            float4 w2v= *(const float4*)(w2c_s + (k+2) * FD + c4);
            float4 w3v= *(const float4*)(w2c_s + (k+3) * FD + c4);
#pragma unroll
            for (int e = 0; e < 2; e++) {
                float4 a = *(const float4*)(ts + (st*2+e) * AST + kc + k);
                acc[e][0] += a.x*w0.x + a.y*w1v.x + a.z*w2v.x + a.w*w3v.x;
                acc[e][1] += a.x*w0.y + a.y*w1v.y + a.z*w2v.y + a.w*w3v.y;
                acc[e][2] += a.x*w0.z + a.y*w1v.z + a.z*w2v.z + a.w*w3v.z;
                acc[e][3] += a.x*w0.w + a.y*w1v.w + a.z*w2v.w + a.w*w3v.w;
            }
        }
        __syncthreads();
    }
#pragma unroll
    for (int e = 0; e < 2; e++) {
        float4 g4 = *(const float4*)(gef + (st*2+e) * AST + c4);
        float s = acc[e][0]*g4.x + acc[e][1]*g4.y + acc[e][2]*g4.z + acc[e][3]*g4.w;
        s += __shfl_xor(s, 1, 64);
        s += __shfl_xor(s, 2, 64);
        s += __shfl_xor(s, 4, 64);
        s += __shfl_xor(s, 8, 64);
        s += __shfl_xor(s, 16, 64);
        int gp = base + st * 2 + e;
        if (cg == e && gp < np) {
            int ii = pis[st * 2 + e], jj = pjs[st * 2 + e];
            float coef = s / pair_d[gp];
            float fx = coef * pair_dx[gp];
            float fy = coef * pair_dy[gp];
            float fz = coef * pair_dz[gp];
            atomicAdd(f_acc + ii*3 + 0, -fx);
            atomicAdd(f_acc + ii*3 + 1, -fy);
            atomicAdd(f_acc + ii*3 + 2, -fz);
            atomicAdd(f_acc + jj*3 + 0, fx);
            atomicAdd(f_acc + jj*3 + 1, fy);
            atomicAdd(f_acc + jj*3 + 2, fz);
        }
    }
}

// ---------------------------------------------------------------- finalize
__global__ __launch_bounds__(256) void fin_kernel(
    const float* __restrict__ v, const float* __restrict__ mass,
    const float* __restrict__ p_eta, const float* __restrict__ f_acc,
    float* __restrict__ out)
{
    __shared__ float red[256];
    int t = threadIdx.x;
    float ke = 0.f;
    float c = p_eta[0] / Q0_F;
    for (int idx = t; idx < 3 * N_ATOMS; idx += 256) {
        int a = idx / 3;
        float vv = v[idx], mi = mass[a];
        out[DVDT_OFF + idx] = (f_acc[idx] - c * vv * mi) / mi;
        out[V_OFF + idx] = vv;
        ke += 0.5f * mi * vv * vv;
    }
    red[t] = ke;
    __syncthreads();
    for (int s = 128; s > 0; s >>= 1) {
        if (t < s) red[t] += red[t + s];
        __syncthreads();
    }
    if (t == 0) {
        float k0 = red[0];
        float e0 = p_eta[0], e1 = p_eta[1], e2 = p_eta[2], e3 = p_eta[3];
        out[PETA_OFF + 0] = 2.f * (k0 - TARGET_KE) - e0 * e1 / QI_F;
        out[PETA_OFF + 1] = e0 * e0 / Q0_F - KT_F - e1 * e2 / QI_F;
        out[PETA_OFF + 2] = e1 * e1 / QI_F - KT_F - e2 * e3 / QI_F;
        out[PETA_OFF + 3] = e2 * e2 / QI_F - KT_F;
    }
}

// ---------------------------------------------------------------- launch
extern "C" void kernel_launch(void* const* d_in, const int* in_sizes, int n_in,
                              void* d_out, int out_size, void* d_ws, size_t ws_size,
                              hipStream_t stream)
{
    const float* v     = (const float*)d_in[0];
    const float* q     = (const float*)d_in[1];
    const float* p_eta = (const float*)d_in[2];
    const float* mass  = (const float*)d_in[3];
    const float* embed = (const float*)d_in[4];
    const float* W1    = (const float*)d_in[5];
    const float* b1    = (const float*)d_in[6];
    const float* W2    = (const float*)d_in[7];
    const float* b2    = (const float*)d_in[8];
    const float* W3    = (const float*)d_in[9];
    const float* wout  = (const float*)d_in[10];
    const int*   z     = (const int*)d_in[11];
    float* out = (float*)d_out;

    float* h     = (float*)d_ws;
    float* W2T   = h + N_ATOMS * FD;
    float* W3T   = W2T + FD * FD;
    float* m     = W3T + FD * FD;
    float* f_acc = m + N_ATOMS * FD;
    float* pair_d  = f_acc + 3 * N_ATOMS;
    float* pair_dx = pair_d + N_ATOMS * MAXN;
    float* pair_dy = pair_dx + N_ATOMS * MAXN;
    float* pair_dz = pair_dy + N_ATOMS * MAXN;
    int* pair_i = (int*)(pair_dz + N_ATOMS * MAXN);
    int* pair_j = pair_i + N_ATOMS * MAXN;
    int* npairs_ctr = pair_j + N_ATOMS * MAXN;

    hipMemsetAsync(npairs_ctr, 0, sizeof(int), stream);

    prep_kernel<<<N_ATOMS, 256, 0, stream>>>(q, z, embed, W2, W3, h, W2T, W3T,
                                             pair_i, pair_j, pair_d,
                                             pair_dx, pair_dy, pair_dz,
                                             npairs_ctr, m, f_acc);
    fwd_kernel<<<FTILES, 256, 0, stream>>>(W1, b1, W2, b2, h, pair_i,
                                           pair_j, pair_d, npairs_ctr, m);
    bwd_kernel<<<BTILES, 256, 0, stream>>>(W1, b1, W2T, h, m, W3, W3T, wout,
                                           pair_i, pair_j, pair_d, pair_dx,
                                           pair_dy, pair_dz, npairs_ctr, f_acc);
    fin_kernel<<<1, 256, 0, stream>>>(v, mass, p_eta, f_acc, out);
}

// Round 3
// 162.479 us; speedup vs baseline: 1.1010x; 1.1010x over previous
//
#include <hip/hip_runtime.h>
#include <math.h>

// Problem constants (match reference)
#define N_ATOMS 768
#define FD 128          // feature width
#define NRBF 32
#define MAXN 64         // per-atom neighbor cap (mean ~26)
#define PPF 32          // fwd: pairs per block (4 pairs x 4 cols per thread)
#define PPBW 16         // bwd: pairs per block (2 pairs x 4 cols per thread)
#define FTILES (N_ATOMS * MAXN / PPF)     // 1536
#define BTILES (N_ATOMS * MAXN / PPBW)    // 3072
#define AST 132         // padded LDS stride for [*][128] tiles (16B-aligned)
#define RST 36          // padded LDS stride for [*][32] rbf tiles

constexpr float  CUT2   = 25.0f;
constexpr float  GAMMA_ = 40.96f;            // 1/(5/32)^2
constexpr float  CSTEP  = 5.0f / 31.0f;      // linspace(0,5,32) step
constexpr double KB_D   = 8.617330337217213e-05;
constexpr double KT_D   = 300.0 * KB_D;
constexpr float  KT_F   = (float)KT_D;
constexpr float  TARGET_KE = (float)(0.5 * 2304.0 * KT_D);
constexpr float  Q0_F   = (float)(2.0 * 2304.0 * KT_D * 400.0);  // Q[0]
constexpr float  QI_F   = (float)(2.0 * KT_D * 400.0);           // Q[1..3]

#define DVDT_OFF 0
#define V_OFF    (3 * N_ATOMS)
#define PETA_OFF (6 * N_ATOMS)

// Hard-won rules (19 rounds of counters):
// 1. NO __launch_bounds__ min-wave hints on GEMM kernels — compiler squeezes
//    VGPRs below demand -> scratch spills -> 100s-of-MB symmetric FETCH/WRITE.
// 2. Reduce register demand STRUCTURALLY — phase-split through LDS.
// 3. fwd wants PPF=32, bwd wants PPBW=16 (R12/R13).
// 4. NEVER put __threadfence / completion counters on the hot grid (R14).
// 5. R18 FAILED: per-wave mbar + reg-gef -> 60.5us. Spreading the mbar GEMV
//    chains across waves doesn't shorten them (nda~1.6 < 4 waves).
// 6. R19 FAILED: LDS weight staging -> 71us. The 8x redundant W2T/W2 stream
//    was already L1-absorbed; staging added 16 barriers + occupancy loss.
// 7. R20 theory: bwd stall = in-block mbar recompute (2 seq 128-step GEMVs
//    x nda, half threads idle, 4 barriers/atom ~ 15K cyc serial). Extract to
//    a dedicated 768-block mbar_kernel (24.6 MFLOP, ~5us); bwd gathers mbar
//    rows directly in ts-fill. bwd: 2 barriers total.

// ---------------------------------------------------------------- prep
__global__ __launch_bounds__(256) void prep_kernel(
    const float* __restrict__ q, const int* __restrict__ z,
    const float* __restrict__ embed, const float* __restrict__ W2,
    const float* __restrict__ W3,
    float* __restrict__ h, float* __restrict__ W2T, float* __restrict__ W3T,
    int* __restrict__ pair_i, int* __restrict__ pair_j,
    float* __restrict__ pair_d, float* __restrict__ pair_dx,
    float* __restrict__ pair_dy, float* __restrict__ pair_dz,
    int* __restrict__ npairs_ctr,
    float* __restrict__ m, float* __restrict__ f_acc)
{
    __shared__ int   nj[MAXN];
    __shared__ float nd[MAXN], ndx[MAXN], ndy[MAXN], ndz[MAXN];
    __shared__ int cnt_s, base_s;
    int i = blockIdx.x, t = threadIdx.x;
    if (t == 0) cnt_s = 0;
    __syncthreads();
    float qx = q[i*3], qy = q[i*3+1], qz = q[i*3+2];
    for (int j = t; j < N_ATOMS; j += 256) {
        if (j == i) continue;
        float dx = qx - q[j*3], dy = qy - q[j*3+1], dz = qz - q[j*3+2];
        float d2 = dx*dx + dy*dy + dz*dz;
        if (d2 < CUT2) {
            int p = atomicAdd(&cnt_s, 1);
            if (p < MAXN) { nj[p] = j; nd[p] = sqrtf(d2);
                            ndx[p] = dx; ndy[p] = dy; ndz[p] = dz; }
        }
    }
    int g = i * 256 + t;                         // 196608 global ids
    if (g < N_ATOMS * FD) { h[g] = embed[z[g >> 7] * FD + (g & 127)]; m[g] = 0.f; }
    int g2 = g - N_ATOMS * FD;
    if (g2 >= 0 && g2 < FD * FD) {
        int r = g2 >> 7, c = g2 & 127;
        W2T[c * FD + r] = W2[g2];
        W3T[c * FD + r] = W3[g2];
    }
    if (g < 3 * N_ATOMS) f_acc[g] = 0.f;
    __syncthreads();
    if (t == 0) base_s = atomicAdd(npairs_ctr, min(cnt_s, MAXN));
    __syncthreads();
    int cnt = min(cnt_s, MAXN), base = base_s;
    if (t < cnt) {
        pair_i[base+t] = i;      pair_j[base+t] = nj[t];
        pair_d[base+t] = nd[t];  pair_dx[base+t] = ndx[t];
        pair_dy[base+t] = ndy[t]; pair_dz[base+t] = ndz[t];
    }
}

// ---------------------------------------------------------------- fwd (PPF=32)
// R16 three-phase register-diet structure (best known; R19 staging reverted).
__global__ __launch_bounds__(256) void fwd_kernel(
    const float* __restrict__ W1, const float* __restrict__ b1,
    const float* __restrict__ W2, const float* __restrict__ b2,
    const float* __restrict__ h,
    const int* __restrict__ pair_i, const int* __restrict__ pair_j,
    const float* __restrict__ pair_d, const int* __restrict__ npairs_ctr,
    float* __restrict__ m)
{
    __shared__ float rbf_s[PPF * RST];    //  4608 B
    __shared__ float a1_s[PPF * AST];     // 16896 B
    __shared__ float filt_s[PPF * AST];   // 16896 B
    __shared__ int   pis[PPF], pjs[PPF];  //   256 B  (total ~38.7 KB)
    int t = threadIdx.x;
    int base = blockIdx.x * PPF;
    int np = npairs_ctr[0];
    if (base >= np) return;

    if (t < PPF) {
        int p = base + t; bool ok = p < np;
        pis[t] = ok ? pair_i[p] : 0;
        pjs[t] = ok ? pair_j[p] : 0;
    }
    for (int idx = t; idx < PPF * NRBF; idx += 256) {
        int p = idx >> 5, k = idx & 31;
        int gp = base + p;
        float d = (gp < np) ? pair_d[gp] : 1.0f;
        float u = d - CSTEP * (float)k;
        rbf_s[p * RST + k] = __expf(-GAMMA_ * u * u);
    }
    __syncthreads();

    // Phase A: a1[p][c] = relu(b1[c] + rbf[p]@W1[:,c]); thread = (c, 16-pair half)
    {
        int c = t & 127, ph = t >> 7;
        float w1c[NRBF];
#pragma unroll
        for (int k = 0; k < NRBF; k++) w1c[k] = W1[k * FD + c];
        float b1c = b1[c];
        for (int p = ph * 16; p < ph * 16 + 16; p++) {
            float u = b1c;
#pragma unroll
            for (int k4 = 0; k4 < NRBF / 4; k4++) {
                float4 r = *(const float4*)(rbf_s + p * RST + k4 * 4);
                u += r.x*w1c[k4*4] + r.y*w1c[k4*4+1] + r.z*w1c[k4*4+2] + r.w*w1c[k4*4+3];
            }
            a1_s[p * AST + c] = fmaxf(u, 0.f);
        }
    }
    __syncthreads();

    // Phase B: filt[p][c4..] = a1[p] @ W2[:,c4..]  (raw; b2 added in phase C)
    {
        int st = t >> 5, cg = t & 31, c4 = 4 * cg;
        float acc[4][4];
#pragma unroll
        for (int e = 0; e < 4; e++) { acc[e][0]=0; acc[e][1]=0; acc[e][2]=0; acc[e][3]=0; }
        for (int k = 0; k < FD; k += 4) {
            float4 w0 = *(const float4*)(W2 + (k+0) * FD + c4);
            float4 w1v= *(const float4*)(W2 + (k+1) * FD + c4);
            float4 w2v= *(const float4*)(W2 + (k+2) * FD + c4);
            float4 w3v= *(const float4*)(W2 + (k+3) * FD + c4);
#pragma unroll
            for (int e = 0; e < 4; e++) {
                float4 a = *(const float4*)(a1_s + (st*4+e) * AST + k);
                acc[e][0] += a.x*w0.x + a.y*w1v.x + a.z*w2v.x + a.w*w3v.x;
                acc[e][1] += a.x*w0.y + a.y*w1v.y + a.z*w2v.y + a.w*w3v.y;
                acc[e][2] += a.x*w0.z + a.y*w1v.z + a.z*w2v.z + a.w*w3v.z;
                acc[e][3] += a.x*w0.w + a.y*w1v.w + a.z*w2v.w + a.w*w3v.w;
            }
        }
#pragma unroll
        for (int e = 0; e < 4; e++) {
            float4 fv; fv.x = acc[e][0]; fv.y = acc[e][1];
            fv.z = acc[e][2]; fv.w = acc[e][3];
            *(float4*)(filt_s + (st*4+e) * AST + c4) = fv;
        }
    }
    __syncthreads();

    // Phase C: m[i,c] += (filt[p][c]+b2[c]) * h[j_p][c]; thread = (c, half)
    {
        int c = t & 127, ph = t >> 7;
        float b2c = b2[c];
        float r = 0.f;
        int p0 = ph * 16;
        int cur_i = pis[p0];
        for (int p = p0; p < p0 + 16; p++) {
            int ip = pis[p];
            if (ip != cur_i) {
                atomicAdd(m + cur_i * FD + c, r);
                r = 0.f; cur_i = ip;
            }
            if (base + p < np)
                r += (filt_s[p * AST + c] + b2c) * h[pjs[p] * FD + c];
        }
        atomicAdd(m + cur_i * FD + c, r);
    }
}

// ---------------------------------------------------------------- mbar (R20)
// One block per atom: mbar_i = W3T @ (wout * gate(m_i @ W3)). 256 threads:
// (c, half) split of each 128-dot; partials combined through LDS.
__global__ __launch_bounds__(256) void mbar_kernel(
    const float* __restrict__ m, const float* __restrict__ W3,
    const float* __restrict__ W3T, const float* __restrict__ wout,
    float* __restrict__ mbar)
{
    __shared__ float mrow[FD];
    __shared__ float gb[FD];
    __shared__ float part[256];
    int i = blockIdx.x, t = threadIdx.x;
    if (t < FD) mrow[t] = m[i * FD + t];
    __syncthreads();
    int c = t & 127, hh = t >> 7;          // hh = 0/1 -> f half
    int f0 = hh * 64;
    float g = 0.f;
#pragma unroll 8
    for (int f = f0; f < f0 + 64; f++) g += mrow[f] * W3[f * FD + c];
    part[t] = g;
    __syncthreads();
    if (t < FD) gb[t] = (part[t] + part[t + 128] > 0.f) ? wout[t] : 0.f;
    __syncthreads();
    float mb = 0.f;
#pragma unroll 8
    for (int f = f0; f < f0 + 64; f++) mb += gb[f] * W3T[f * FD + c];
    part[t] = mb;
    __syncthreads();
    if (t < FD) mbar[i * FD + t] = part[t] + part[t + 128];
}

// ---------------------------------------------------------------- bwd (PPBW=16)
// R20 lean structure: stage -> ts-fill (direct mbar gather) -> gef -> GEMM.
// 2 barriers total; no in-block mbar recompute.
__global__ __launch_bounds__(256) void bwd_kernel(
    const float* __restrict__ W1, const float* __restrict__ b1,
    const float* __restrict__ W2T, const float* __restrict__ h,
    const float* __restrict__ mbar,
    const int* __restrict__ pair_i, const int* __restrict__ pair_j,
    const float* __restrict__ pair_d, const float* __restrict__ pair_dx,
    const float* __restrict__ pair_dy, const float* __restrict__ pair_dz,
    const int* __restrict__ npairs_ctr, float* __restrict__ f_acc)
{
    __shared__ float rbf_s[PPBW * RST];    //  2304 B
    __shared__ float crbf_s[PPBW * RST];   //  2304 B
    __shared__ float ts[PPBW * AST];       //  8448 B
    __shared__ float gef[PPBW * AST];      //  8448 B
    __shared__ int   pis[PPBW], pjs[PPBW]; //   128 B  (total ~21.6 KB)
    int t = threadIdx.x;
    int base = blockIdx.x * PPBW;
    int np = npairs_ctr[0];
    if (base >= np) return;

    if (t < PPBW) {
        int p = base + t; bool ok = p < np;
        pis[t] = ok ? pair_i[p] : 0;
        pjs[t] = ok ? pair_j[p] : 0;
    }
    for (int idx = t; idx < PPBW * NRBF; idx += 256) {
        int p = idx >> 5, k = idx & 31;
        int gp = base + p;
        float d = (gp < np) ? pair_d[gp] : 1.0f;
        float u = d - CSTEP * (float)k;
        float r = __expf(-GAMMA_ * u * u);
        rbf_s[p * RST + k]  = r;
        crbf_s[p * RST + k] = -2.f * GAMMA_ * u * r;
    }
    __syncthreads();                       // pis/pjs + rbf/crbf ready

    // ts-fill: ts[p][c] = mbar[i_p][c] * h[j_p][c]  (2 float4 gathers/thread)
    for (int idx = t; idx < PPBW * 32; idx += 256) {
        int p = idx >> 5, c4g = (idx & 31) * 4;
        float4 mb4 = *(const float4*)(mbar + pis[p] * FD + c4g);
        float4 hj4 = *(const float4*)(h    + pjs[p] * FD + c4g);
        float4 tv; tv.x = mb4.x*hj4.x; tv.y = mb4.y*hj4.y;
        tv.z = mb4.z*hj4.z; tv.w = mb4.w*hj4.w;
        *(float4*)(ts + p * AST + c4g) = tv;
    }

    // gef phase: thread = (c, 8-pair half); w1c regs die at phase end
    {
        int c = t & 127, ph = t >> 7;
        float w1c[NRBF];
#pragma unroll
        for (int k = 0; k < NRBF; k++) w1c[k] = W1[k * FD + c];
        float b1c = b1[c];
        for (int p = ph * 8; p < ph * 8 + 8; p++) {
            float u1 = b1c, ef = 0.f;
#pragma unroll
            for (int k4 = 0; k4 < NRBF / 4; k4++) {
                float4 r = *(const float4*)(rbf_s  + p * RST + k4 * 4);
                float4 cd= *(const float4*)(crbf_s + p * RST + k4 * 4);
                u1 += r.x*w1c[k4*4] + r.y*w1c[k4*4+1] + r.z*w1c[k4*4+2] + r.w*w1c[k4*4+3];
                ef += cd.x*w1c[k4*4] + cd.y*w1c[k4*4+1] + cd.z*w1c[k4*4+2] + cd.w*w1c[k4*4+3];
            }
            gef[p * AST + c] = (u1 > 0.f) ? ef : 0.f;
        }
    }
    __syncthreads();                       // ts + gef ready

    // GEMM: du1[p][c4..] = ts[p] @ W2T[:,c4..]; fold gef immediately.
    int st = t >> 5, cg = t & 31, c4 = 4 * cg;
    float acc[2][4];
#pragma unroll
    for (int e = 0; e < 2; e++) { acc[e][0]=0; acc[e][1]=0; acc[e][2]=0; acc[e][3]=0; }
    for (int k = 0; k < FD; k += 4) {
        float4 w0 = *(const float4*)(W2T + (k+0) * FD + c4);
        float4 w1v= *(const float4*)(W2T + (k+1) * FD + c4);
        float4 w2v= *(const float4*)(W2T + (k+2) * FD + c4);
        float4 w3v= *(const float4*)(W2T + (k+3) * FD + c4);
#pragma unroll
        for (int e = 0; e < 2; e++) {
            float4 a = *(const float4*)(ts + (st*2+e) * AST + k);
            acc[e][0] += a.x*w0.x + a.y*w1v.x + a.z*w2v.x + a.w*w3v.x;
            acc[e][1] += a.x*w0.y + a.y*w1v.y + a.z*w2v.y + a.w*w3v.y;
            acc[e][2] += a.x*w0.z + a.y*w1v.z + a.z*w2v.z + a.w*w3v.z;
            acc[e][3] += a.x*w0.w + a.y*w1v.w + a.z*w2v.w + a.w*w3v.w;
        }
    }
#pragma unroll
    for (int e = 0; e < 2; e++) {
        float4 g4 = *(const float4*)(gef + (st*2+e) * AST + c4);
        float s = acc[e][0]*g4.x + acc[e][1]*g4.y + acc[e][2]*g4.z + acc[e][3]*g4.w;
        s += __shfl_xor(s, 1, 64);
        s += __shfl_xor(s, 2, 64);
        s += __shfl_xor(s, 4, 64);
        s += __shfl_xor(s, 8, 64);
        s += __shfl_xor(s, 16, 64);
        int gp = base + st * 2 + e;
        if (cg == e && gp < np) {
            int ii = pis[st * 2 + e], jj = pjs[st * 2 + e];
            float coef = s / pair_d[gp];
            float fx = coef * pair_dx[gp];
            float fy = coef * pair_dy[gp];
            float fz = coef * pair_dz[gp];
            atomicAdd(f_acc + ii*3 + 0, -fx);
            atomicAdd(f_acc + ii*3 + 1, -fy);
            atomicAdd(f_acc + ii*3 + 2, -fz);
            atomicAdd(f_acc + jj*3 + 0, fx);
            atomicAdd(f_acc + jj*3 + 1, fy);
            atomicAdd(f_acc + jj*3 + 2, fz);
        }
    }
}

// ---------------------------------------------------------------- finalize
__global__ __launch_bounds__(256) void fin_kernel(
    const float* __restrict__ v, const float* __restrict__ mass,
    const float* __restrict__ p_eta, const float* __restrict__ f_acc,
    float* __restrict__ out)
{
    __shared__ float red[256];
    int t = threadIdx.x;
    float ke = 0.f;
    float c = p_eta[0] / Q0_F;
    for (int idx = t; idx < 3 * N_ATOMS; idx += 256) {
        int a = idx / 3;
        float vv = v[idx], mi = mass[a];
        out[DVDT_OFF + idx] = (f_acc[idx] - c * vv * mi) / mi;
        out[V_OFF + idx] = vv;
        ke += 0.5f * mi * vv * vv;
    }
    red[t] = ke;
    __syncthreads();
    for (int s = 128; s > 0; s >>= 1) {
        if (t < s) red[t] += red[t + s];
        __syncthreads();
    }
    if (t == 0) {
        float k0 = red[0];
        float e0 = p_eta[0], e1 = p_eta[1], e2 = p_eta[2], e3 = p_eta[3];
        out[PETA_OFF + 0] = 2.f * (k0 - TARGET_KE) - e0 * e1 / QI_F;
        out[PETA_OFF + 1] = e0 * e0 / Q0_F - KT_F - e1 * e2 / QI_F;
        out[PETA_OFF + 2] = e1 * e1 / QI_F - KT_F - e2 * e3 / QI_F;
        out[PETA_OFF + 3] = e2 * e2 / QI_F - KT_F;
    }
}

// ---------------------------------------------------------------- launch
extern "C" void kernel_launch(void* const* d_in, const int* in_sizes, int n_in,
                              void* d_out, int out_size, void* d_ws, size_t ws_size,
                              hipStream_t stream)
{
    const float* v     = (const float*)d_in[0];
    const float* q     = (const float*)d_in[1];
    const float* p_eta = (const float*)d_in[2];
    const float* mass  = (const float*)d_in[3];
    const float* embed = (const float*)d_in[4];
    const float* W1    = (const float*)d_in[5];
    const float* b1    = (const float*)d_in[6];
    const float* W2    = (const float*)d_in[7];
    const float* b2    = (const float*)d_in[8];
    const float* W3    = (const float*)d_in[9];
    const float* wout  = (const float*)d_in[10];
    const int*   z     = (const int*)d_in[11];
    float* out = (float*)d_out;

    float* h     = (float*)d_ws;
    float* W2T   = h + N_ATOMS * FD;
    float* W3T   = W2T + FD * FD;
    float* m     = W3T + FD * FD;
    float* f_acc = m + N_ATOMS * FD;
    float* pair_d  = f_acc + 3 * N_ATOMS;
    float* pair_dx = pair_d + N_ATOMS * MAXN;
    float* pair_dy = pair_dx + N_ATOMS * MAXN;
    float* pair_dz = pair_dy + N_ATOMS * MAXN;
    int* pair_i = (int*)(pair_dz + N_ATOMS * MAXN);
    int* pair_j = pair_i + N_ATOMS * MAXN;
    int* npairs_ctr = pair_j + N_ATOMS * MAXN;
    float* mbar  = (float*)(npairs_ctr + 64);   // 64-int pad for alignment

    hipMemsetAsync(npairs_ctr, 0, sizeof(int), stream);

    prep_kernel<<<N_ATOMS, 256, 0, stream>>>(q, z, embed, W2, W3, h, W2T, W3T,
                                             pair_i, pair_j, pair_d,
                                             pair_dx, pair_dy, pair_dz,
                                             npairs_ctr, m, f_acc);
    fwd_kernel<<<FTILES, 256, 0, stream>>>(W1, b1, W2, b2, h, pair_i,
                                           pair_j, pair_d, npairs_ctr, m);
    mbar_kernel<<<N_ATOMS, 256, 0, stream>>>(m, W3, W3T, wout, mbar);
    bwd_kernel<<<BTILES, 256, 0, stream>>>(W1, b1, W2T, h, mbar,
                                           pair_i, pair_j, pair_d, pair_dx,
                                           pair_dy, pair_dz, npairs_ctr, f_acc);
    fin_kernel<<<1, 256, 0, stream>>>(v, mass, p_eta, f_acc, out);
}

// Round 4
// 161.292 us; speedup vs baseline: 1.1091x; 1.0074x over previous
//
#include <hip/hip_runtime.h>
#include <math.h>

// Problem constants (match reference)
#define N_ATOMS 768
#define FD 128          // feature width
#define NRBF 32
#define MAXN 64         // per-atom neighbor cap (mean ~26)
#define PPF 32          // fwd: pairs per block (4 pairs x 4 cols per thread)
#define PPBW 32         // bwd: pairs per block (R21: 4 pairs x 4 cols per thread)
#define FTILES (N_ATOMS * MAXN / PPF)     // 1536
#define BTILES (N_ATOMS * MAXN / PPBW)    // 1536
#define AST 132         // padded LDS stride for [*][128] tiles (16B-aligned)
#define RST 36          // padded LDS stride for [*][32] rbf tiles

constexpr float  CUT2   = 25.0f;
constexpr float  GAMMA_ = 40.96f;            // 1/(5/32)^2
constexpr float  CSTEP  = 5.0f / 31.0f;      // linspace(0,5,32) step
constexpr double KB_D   = 8.617330337217213e-05;
constexpr double KT_D   = 300.0 * KB_D;
constexpr float  KT_F   = (float)KT_D;
constexpr float  TARGET_KE = (float)(0.5 * 2304.0 * KT_D);
constexpr float  Q0_F   = (float)(2.0 * 2304.0 * KT_D * 400.0);  // Q[0]
constexpr float  QI_F   = (float)(2.0 * KT_D * 400.0);           // Q[1..3]

#define DVDT_OFF 0
#define V_OFF    (3 * N_ATOMS)
#define PETA_OFF (6 * N_ATOMS)

// Hard-won rules (20 rounds of counters):
// 1. NO __launch_bounds__ min-wave hints on GEMM kernels (spill cliff).
// 2. Reduce register demand STRUCTURALLY — phase-split through LDS.
// 3. NEVER put __threadfence / completion counters on the hot grid (R14).
// 4. R18 FAILED: per-wave mbar spread doesn't shorten chains (nda~1.6 < 4).
// 5. R19 FAILED: LDS weight staging — the 8x redundant weight stream is
//    L1-absorbed; staging added barriers + occupancy loss.
// 6. R20 WIN: mbar extracted to its own 768-block kernel (bwd 56->45.7,
//    VALUBusy 23->32). Serial in-block GEMV chains were real cost.
// 7. R21 theory: bwd GEMM = 128 W2T loads + 1024 FMA/thread is load-latency
//    dominated (fwd phase B: same 128 loads + 2048 FMA runs FASTER incl.
//    two extra phases). PPBW 16->32 doubles FMA per load (mirrors proven
//    fwd structure), halves total W2T stream. Old PPBW=16 preference
//    predates the R17/R20 bwd restructure.

// ---------------------------------------------------------------- prep
__global__ __launch_bounds__(256) void prep_kernel(
    const float* __restrict__ q, const int* __restrict__ z,
    const float* __restrict__ embed, const float* __restrict__ W2,
    const float* __restrict__ W3,
    float* __restrict__ h, float* __restrict__ W2T, float* __restrict__ W3T,
    int* __restrict__ pair_i, int* __restrict__ pair_j,
    float* __restrict__ pair_d, float* __restrict__ pair_dx,
    float* __restrict__ pair_dy, float* __restrict__ pair_dz,
    int* __restrict__ npairs_ctr,
    float* __restrict__ m, float* __restrict__ f_acc)
{
    __shared__ int   nj[MAXN];
    __shared__ float nd[MAXN], ndx[MAXN], ndy[MAXN], ndz[MAXN];
    __shared__ int cnt_s, base_s;
    int i = blockIdx.x, t = threadIdx.x;
    if (t == 0) cnt_s = 0;
    __syncthreads();
    float qx = q[i*3], qy = q[i*3+1], qz = q[i*3+2];
    for (int j = t; j < N_ATOMS; j += 256) {
        if (j == i) continue;
        float dx = qx - q[j*3], dy = qy - q[j*3+1], dz = qz - q[j*3+2];
        float d2 = dx*dx + dy*dy + dz*dz;
        if (d2 < CUT2) {
            int p = atomicAdd(&cnt_s, 1);
            if (p < MAXN) { nj[p] = j; nd[p] = sqrtf(d2);
                            ndx[p] = dx; ndy[p] = dy; ndz[p] = dz; }
        }
    }
    int g = i * 256 + t;                         // 196608 global ids
    if (g < N_ATOMS * FD) { h[g] = embed[z[g >> 7] * FD + (g & 127)]; m[g] = 0.f; }
    int g2 = g - N_ATOMS * FD;
    if (g2 >= 0 && g2 < FD * FD) {
        int r = g2 >> 7, c = g2 & 127;
        W2T[c * FD + r] = W2[g2];
        W3T[c * FD + r] = W3[g2];
    }
    if (g < 3 * N_ATOMS) f_acc[g] = 0.f;
    __syncthreads();
    if (t == 0) base_s = atomicAdd(npairs_ctr, min(cnt_s, MAXN));
    __syncthreads();
    int cnt = min(cnt_s, MAXN), base = base_s;
    if (t < cnt) {
        pair_i[base+t] = i;      pair_j[base+t] = nj[t];
        pair_d[base+t] = nd[t];  pair_dx[base+t] = ndx[t];
        pair_dy[base+t] = ndy[t]; pair_dz[base+t] = ndz[t];
    }
}

// ---------------------------------------------------------------- fwd (PPF=32)
// R16 three-phase register-diet structure (best known).
__global__ __launch_bounds__(256) void fwd_kernel(
    const float* __restrict__ W1, const float* __restrict__ b1,
    const float* __restrict__ W2, const float* __restrict__ b2,
    const float* __restrict__ h,
    const int* __restrict__ pair_i, const int* __restrict__ pair_j,
    const float* __restrict__ pair_d, const int* __restrict__ npairs_ctr,
    float* __restrict__ m)
{
    __shared__ float rbf_s[PPF * RST];    //  4608 B
    __shared__ float a1_s[PPF * AST];     // 16896 B
    __shared__ float filt_s[PPF * AST];   // 16896 B
    __shared__ int   pis[PPF], pjs[PPF];  //   256 B  (total ~38.7 KB)
    int t = threadIdx.x;
    int base = blockIdx.x * PPF;
    int np = npairs_ctr[0];
    if (base >= np) return;

    if (t < PPF) {
        int p = base + t; bool ok = p < np;
        pis[t] = ok ? pair_i[p] : 0;
        pjs[t] = ok ? pair_j[p] : 0;
    }
    for (int idx = t; idx < PPF * NRBF; idx += 256) {
        int p = idx >> 5, k = idx & 31;
        int gp = base + p;
        float d = (gp < np) ? pair_d[gp] : 1.0f;
        float u = d - CSTEP * (float)k;
        rbf_s[p * RST + k] = __expf(-GAMMA_ * u * u);
    }
    __syncthreads();

    // Phase A: a1[p][c] = relu(b1[c] + rbf[p]@W1[:,c]); thread = (c, 16-pair half)
    {
        int c = t & 127, ph = t >> 7;
        float w1c[NRBF];
#pragma unroll
        for (int k = 0; k < NRBF; k++) w1c[k] = W1[k * FD + c];
        float b1c = b1[c];
        for (int p = ph * 16; p < ph * 16 + 16; p++) {
            float u = b1c;
#pragma unroll
            for (int k4 = 0; k4 < NRBF / 4; k4++) {
                float4 r = *(const float4*)(rbf_s + p * RST + k4 * 4);
                u += r.x*w1c[k4*4] + r.y*w1c[k4*4+1] + r.z*w1c[k4*4+2] + r.w*w1c[k4*4+3];
            }
            a1_s[p * AST + c] = fmaxf(u, 0.f);
        }
    }
    __syncthreads();

    // Phase B: filt[p][c4..] = a1[p] @ W2[:,c4..]  (raw; b2 added in phase C)
    {
        int st = t >> 5, cg = t & 31, c4 = 4 * cg;
        float acc[4][4];
#pragma unroll
        for (int e = 0; e < 4; e++) { acc[e][0]=0; acc[e][1]=0; acc[e][2]=0; acc[e][3]=0; }
        for (int k = 0; k < FD; k += 4) {
            float4 w0 = *(const float4*)(W2 + (k+0) * FD + c4);
            float4 w1v= *(const float4*)(W2 + (k+1) * FD + c4);
            float4 w2v= *(const float4*)(W2 + (k+2) * FD + c4);
            float4 w3v= *(const float4*)(W2 + (k+3) * FD + c4);
#pragma unroll
            for (int e = 0; e < 4; e++) {
                float4 a = *(const float4*)(a1_s + (st*4+e) * AST + k);
                acc[e][0] += a.x*w0.x + a.y*w1v.x + a.z*w2v.x + a.w*w3v.x;
                acc[e][1] += a.x*w0.y + a.y*w1v.y + a.z*w2v.y + a.w*w3v.y;
                acc[e][2] += a.x*w0.z + a.y*w1v.z + a.z*w2v.z + a.w*w3v.z;
                acc[e][3] += a.x*w0.w + a.y*w1v.w + a.z*w2v.w + a.w*w3v.w;
            }
        }
#pragma unroll
        for (int e = 0; e < 4; e++) {
            float4 fv; fv.x = acc[e][0]; fv.y = acc[e][1];
            fv.z = acc[e][2]; fv.w = acc[e][3];
            *(float4*)(filt_s + (st*4+e) * AST + c4) = fv;
        }
    }
    __syncthreads();

    // Phase C: m[i,c] += (filt[p][c]+b2[c]) * h[j_p][c]; thread = (c, half)
    {
        int c = t & 127, ph = t >> 7;
        float b2c = b2[c];
        float r = 0.f;
        int p0 = ph * 16;
        int cur_i = pis[p0];
        for (int p = p0; p < p0 + 16; p++) {
            int ip = pis[p];
            if (ip != cur_i) {
                atomicAdd(m + cur_i * FD + c, r);
                r = 0.f; cur_i = ip;
            }
            if (base + p < np)
                r += (filt_s[p * AST + c] + b2c) * h[pjs[p] * FD + c];
        }
        atomicAdd(m + cur_i * FD + c, r);
    }
}

// ---------------------------------------------------------------- mbar (R20)
// One block per atom: mbar_i = W3T @ (wout * gate(m_i @ W3)). 256 threads:
// (c, half) split of each 128-dot; partials combined through LDS.
__global__ __launch_bounds__(256) void mbar_kernel(
    const float* __restrict__ m, const float* __restrict__ W3,
    const float* __restrict__ W3T, const float* __restrict__ wout,
    float* __restrict__ mbar)
{
    __shared__ float mrow[FD];
    __shared__ float gb[FD];
    __shared__ float part[256];
    int i = blockIdx.x, t = threadIdx.x;
    if (t < FD) mrow[t] = m[i * FD + t];
    __syncthreads();
    int c = t & 127, hh = t >> 7;          // hh = 0/1 -> f half
    int f0 = hh * 64;
    float g = 0.f;
#pragma unroll 8
    for (int f = f0; f < f0 + 64; f++) g += mrow[f] * W3[f * FD + c];
    part[t] = g;
    __syncthreads();
    if (t < FD) gb[t] = (part[t] + part[t + 128] > 0.f) ? wout[t] : 0.f;
    __syncthreads();
    float mb = 0.f;
#pragma unroll 8
    for (int f = f0; f < f0 + 64; f++) mb += gb[f] * W3T[f * FD + c];
    part[t] = mb;
    __syncthreads();
    if (t < FD) mbar[i * FD + t] = part[t] + part[t + 128];
}

// ---------------------------------------------------------------- bwd (PPBW=32)
// R20 lean structure + R21 tile: stage -> ts-fill -> gef -> GEMM (acc[4][4],
// mirrors proven fwd phase B). 2 barriers total.
__global__ __launch_bounds__(256) void bwd_kernel(
    const float* __restrict__ W1, const float* __restrict__ b1,
    const float* __restrict__ W2T, const float* __restrict__ h,
    const float* __restrict__ mbar,
    const int* __restrict__ pair_i, const int* __restrict__ pair_j,
    const float* __restrict__ pair_d, const float* __restrict__ pair_dx,
    const float* __restrict__ pair_dy, const float* __restrict__ pair_dz,
    const int* __restrict__ npairs_ctr, float* __restrict__ f_acc)
{
    __shared__ float rbf_s[PPBW * RST];    //  4608 B
    __shared__ float crbf_s[PPBW * RST];   //  4608 B
    __shared__ float ts[PPBW * AST];       // 16896 B
    __shared__ float gef[PPBW * AST];      // 16896 B
    __shared__ int   pis[PPBW], pjs[PPBW]; //   256 B  (total ~43.3 KB)
    int t = threadIdx.x;
    int base = blockIdx.x * PPBW;
    int np = npairs_ctr[0];
    if (base >= np) return;

    if (t < PPBW) {
        int p = base + t; bool ok = p < np;
        pis[t] = ok ? pair_i[p] : 0;
        pjs[t] = ok ? pair_j[p] : 0;
    }
    for (int idx = t; idx < PPBW * NRBF; idx += 256) {
        int p = idx >> 5, k = idx & 31;
        int gp = base + p;
        float d = (gp < np) ? pair_d[gp] : 1.0f;
        float u = d - CSTEP * (float)k;
        float r = __expf(-GAMMA_ * u * u);
        rbf_s[p * RST + k]  = r;
        crbf_s[p * RST + k] = -2.f * GAMMA_ * u * r;
    }
    __syncthreads();                       // pis/pjs + rbf/crbf ready

    // ts-fill: ts[p][c] = mbar[i_p][c] * h[j_p][c]  (4 float4-pair gathers/thread)
    for (int idx = t; idx < PPBW * 32; idx += 256) {
        int p = idx >> 5, c4g = (idx & 31) * 4;
        float4 mb4 = *(const float4*)(mbar + pis[p] * FD + c4g);
        float4 hj4 = *(const float4*)(h    + pjs[p] * FD + c4g);
        float4 tv; tv.x = mb4.x*hj4.x; tv.y = mb4.y*hj4.y;
        tv.z = mb4.z*hj4.z; tv.w = mb4.w*hj4.w;
        *(float4*)(ts + p * AST + c4g) = tv;
    }

    // gef phase: thread = (c, 16-pair half); w1c regs die at phase end
    {
        int c = t & 127, ph = t >> 7;
        float w1c[NRBF];
#pragma unroll
        for (int k = 0; k < NRBF; k++) w1c[k] = W1[k * FD + c];
        float b1c = b1[c];
        for (int p = ph * 16; p < ph * 16 + 16; p++) {
            float u1 = b1c, ef = 0.f;
#pragma unroll
            for (int k4 = 0; k4 < NRBF / 4; k4++) {
                float4 r = *(const float4*)(rbf_s  + p * RST + k4 * 4);
                float4 cd= *(const float4*)(crbf_s + p * RST + k4 * 4);
                u1 += r.x*w1c[k4*4] + r.y*w1c[k4*4+1] + r.z*w1c[k4*4+2] + r.w*w1c[k4*4+3];
                ef += cd.x*w1c[k4*4] + cd.y*w1c[k4*4+1] + cd.z*w1c[k4*4+2] + cd.w*w1c[k4*4+3];
            }
            gef[p * AST + c] = (u1 > 0.f) ? ef : 0.f;
        }
    }
    __syncthreads();                       // ts + gef ready

    // GEMM: du1[p][c4..] = ts[p] @ W2T[:,c4..]; fold gef immediately.
    // Thread (st,cg): pairs st*4..st*4+3, cols c4..c4+3 (= fwd phase B shape).
    int st = t >> 5, cg = t & 31, c4 = 4 * cg;
    float acc[4][4];
#pragma unroll
    for (int e = 0; e < 4; e++) { acc[e][0]=0; acc[e][1]=0; acc[e][2]=0; acc[e][3]=0; }
    for (int k = 0; k < FD; k += 4) {
        float4 w0 = *(const float4*)(W2T + (k+0) * FD + c4);
        float4 w1v= *(const float4*)(W2T + (k+1) * FD + c4);
        float4 w2v= *(const float4*)(W2T + (k+2) * FD + c4);
        float4 w3v= *(const float4*)(W2T + (k+3) * FD + c4);
#pragma unroll
        for (int e = 0; e < 4; e++) {
            float4 a = *(const float4*)(ts + (st*4+e) * AST + k);
            acc[e][0] += a.x*w0.x + a.y*w1v.x + a.z*w2v.x + a.w*w3v.x;
            acc[e][1] += a.x*w0.y + a.y*w1v.y + a.z*w2v.y + a.w*w3v.y;
            acc[e][2] += a.x*w0.z + a.y*w1v.z + a.z*w2v.z + a.w*w3v.z;
            acc[e][3] += a.x*w0.w + a.y*w1v.w + a.z*w2v.w + a.w*w3v.w;
        }
    }
#pragma unroll
    for (int e = 0; e < 4; e++) {
        float4 g4 = *(const float4*)(gef + (st*4+e) * AST + c4);
        float s = acc[e][0]*g4.x + acc[e][1]*g4.y + acc[e][2]*g4.z + acc[e][3]*g4.w;
        s += __shfl_xor(s, 1, 64);
        s += __shfl_xor(s, 2, 64);
        s += __shfl_xor(s, 4, 64);
        s += __shfl_xor(s, 8, 64);
        s += __shfl_xor(s, 16, 64);
        int gp = base + st * 4 + e;
        if (cg == e && gp < np) {
            int ii = pis[st * 4 + e], jj = pjs[st * 4 + e];
            float coef = s / pair_d[gp];
            float fx = coef * pair_dx[gp];
            float fy = coef * pair_dy[gp];
            float fz = coef * pair_dz[gp];
            atomicAdd(f_acc + ii*3 + 0, -fx);
            atomicAdd(f_acc + ii*3 + 1, -fy);
            atomicAdd(f_acc + ii*3 + 2, -fz);
            atomicAdd(f_acc + jj*3 + 0, fx);
            atomicAdd(f_acc + jj*3 + 1, fy);
            atomicAdd(f_acc + jj*3 + 2, fz);
        }
    }
}

// ---------------------------------------------------------------- finalize
__global__ __launch_bounds__(256) void fin_kernel(
    const float* __restrict__ v, const float* __restrict__ mass,
    const float* __restrict__ p_eta, const float* __restrict__ f_acc,
    float* __restrict__ out)
{
    __shared__ float red[256];
    int t = threadIdx.x;
    float ke = 0.f;
    float c = p_eta[0] / Q0_F;
    for (int idx = t; idx < 3 * N_ATOMS; idx += 256) {
        int a = idx / 3;
        float vv = v[idx], mi = mass[a];
        out[DVDT_OFF + idx] = (f_acc[idx] - c * vv * mi) / mi;
        out[V_OFF + idx] = vv;
        ke += 0.5f * mi * vv * vv;
    }
    red[t] = ke;
    __syncthreads();
    for (int s = 128; s > 0; s >>= 1) {
        if (t < s) red[t] += red[t + s];
        __syncthreads();
    }
    if (t == 0) {
        float k0 = red[0];
        float e0 = p_eta[0], e1 = p_eta[1], e2 = p_eta[2], e3 = p_eta[3];
        out[PETA_OFF + 0] = 2.f * (k0 - TARGET_KE) - e0 * e1 / QI_F;
        out[PETA_OFF + 1] = e0 * e0 / Q0_F - KT_F - e1 * e2 / QI_F;
        out[PETA_OFF + 2] = e1 * e1 / QI_F - KT_F - e2 * e3 / QI_F;
        out[PETA_OFF + 3] = e2 * e2 / QI_F - KT_F;
    }
}

// ---------------------------------------------------------------- launch
extern "C" void kernel_launch(void* const* d_in, const int* in_sizes, int n_in,
                              void* d_out, int out_size, void* d_ws, size_t ws_size,
                              hipStream_t stream)
{
    const float* v     = (const float*)d_in[0];
    const float* q     = (const float*)d_in[1];
    const float* p_eta = (const float*)d_in[2];
    const float* mass  = (const float*)d_in[3];
    const float* embed = (const float*)d_in[4];
    const float* W1    = (const float*)d_in[5];
    const float* b1    = (const float*)d_in[6];
    const float* W2    = (const float*)d_in[7];
    const float* b2    = (const float*)d_in[8];
    const float* W3    = (const float*)d_in[9];
    const float* wout  = (const float*)d_in[10];
    const int*   z     = (const int*)d_in[11];
    float* out = (float*)d_out;

    float* h     = (float*)d_ws;
    float* W2T   = h + N_ATOMS * FD;
    float* W3T   = W2T + FD * FD;
    float* m     = W3T + FD * FD;
    float* f_acc = m + N_ATOMS * FD;
    float* pair_d  = f_acc + 3 * N_ATOMS;
    float* pair_dx = pair_d + N_ATOMS * MAXN;
    float* pair_dy = pair_dx + N_ATOMS * MAXN;
    float* pair_dz = pair_dy + N_ATOMS * MAXN;
    int* pair_i = (int*)(pair_dz + N_ATOMS * MAXN);
    int* pair_j = pair_i + N_ATOMS * MAXN;
    int* npairs_ctr = pair_j + N_ATOMS * MAXN;
    float* mbar  = (float*)(npairs_ctr + 64);   // 64-int pad for alignment

    hipMemsetAsync(npairs_ctr, 0, sizeof(int), stream);

    prep_kernel<<<N_ATOMS, 256, 0, stream>>>(q, z, embed, W2, W3, h, W2T, W3T,
                                             pair_i, pair_j, pair_d,
                                             pair_dx, pair_dy, pair_dz,
                                             npairs_ctr, m, f_acc);
    fwd_kernel<<<FTILES, 256, 0, stream>>>(W1, b1, W2, b2, h, pair_i,
                                           pair_j, pair_d, npairs_ctr, m);
    mbar_kernel<<<N_ATOMS, 256, 0, stream>>>(m, W3, W3T, wout, mbar);
    bwd_kernel<<<BTILES, 256, 0, stream>>>(W1, b1, W2T, h, mbar,
                                           pair_i, pair_j, pair_d, pair_dx,
                                           pair_dy, pair_dz, npairs_ctr, f_acc);
    fin_kernel<<<1, 256, 0, stream>>>(v, mass, p_eta, f_acc, out);
}

// Round 5
// 156.170 us; speedup vs baseline: 1.1455x; 1.0328x over previous
//
#include <hip/hip_runtime.h>
#include <math.h>

// Problem constants (match reference)
#define N_ATOMS 768
#define FD 128          // feature width
#define NRBF 32
#define MAXN 64         // per-atom neighbor cap (mean ~26)
#define PPF 32          // fwd: pairs per block (4 pairs x 4 cols per thread)
#define PPBW 32         // bwd: pairs per block (2 M-tiles of 16)
#define FTILES (N_ATOMS * MAXN / PPF)     // 1536
#define BTILES (N_ATOMS * MAXN / PPBW)    // 1536
#define AST 132         // padded LDS stride for [*][128] f32 tiles
#define RST 36          // padded LDS stride for [*][32] rbf tiles
#define TST 136         // padded LDS stride for [*][128] bf16 (ushort) tiles

constexpr float  CUT2   = 25.0f;
constexpr float  GAMMA_ = 40.96f;            // 1/(5/32)^2
constexpr float  CSTEP  = 5.0f / 31.0f;      // linspace(0,5,32) step
constexpr double KB_D   = 8.617330337217213e-05;
constexpr double KT_D   = 300.0 * KB_D;
constexpr float  KT_F   = (float)KT_D;
constexpr float  TARGET_KE = (float)(0.5 * 2304.0 * KT_D);
constexpr float  Q0_F   = (float)(2.0 * 2304.0 * KT_D * 400.0);  // Q[0]
constexpr float  QI_F   = (float)(2.0 * KT_D * 400.0);           // Q[1..3]

#define DVDT_OFF 0
#define V_OFF    (3 * N_ATOMS)
#define PETA_OFF (6 * N_ATOMS)

using short8v = __attribute__((ext_vector_type(8))) short;
using f32x4   = __attribute__((ext_vector_type(4))) float;

__device__ __forceinline__ unsigned short f2bf(float x) {
    unsigned int u = __float_as_uint(x);
    u += 0x7FFF + ((u >> 16) & 1);           // round-to-nearest-even
    return (unsigned short)(u >> 16);
}
__device__ __forceinline__ float bf2f(unsigned short h) {
    return __uint_as_float(((unsigned int)h) << 16);
}

// Hard-won rules (21 rounds of counters):
// 1. NO __launch_bounds__ min-wave hints on GEMM kernels (spill cliff).
// 2. Reduce register demand STRUCTURALLY — phase-split through LDS.
// 3. NEVER put __threadfence / completion counters on the hot grid (R14).
// 4. R18 FAILED: per-wave mbar spread doesn't shorten chains (nda~1.6 < 4).
// 5. R19 FAILED: LDS weight staging — redundant weight stream is L1-absorbed.
// 6. R20 WIN: mbar extracted to own 768-block kernel (bwd 56->45.7).
// 7. R21 NEUTRAL: PPBW 16->32 (44.7us). GEMM limited by neither load
//    throughput nor FMA issue -> in-phase L2-latency stalls on the weight
//    stream (all waves barrier-synced, same k-row, 128x per pass).
// 8. R22: bwd GEMM -> MFMA 16x16x32_bf16 with hi/lo split-fp32 (AhBh+AhBl+
//    AlBh; err ~2^-17). 48 MFMA/wave replaces ~16K vector FMA; weight loads
//    16 ushort8/lane (pre-split in prep, [c][k] layout). gef stays fp32,
//    folded in epilogue via 16-lane shuffle reduce.

// ---------------------------------------------------------------- prep
__global__ __launch_bounds__(256) void prep_kernel(
    const float* __restrict__ q, const int* __restrict__ z,
    const float* __restrict__ embed, const float* __restrict__ W2,
    const float* __restrict__ W3,
    float* __restrict__ h, float* __restrict__ W2T, float* __restrict__ W3T,
    unsigned short* __restrict__ w2bh, unsigned short* __restrict__ w2bl,
    int* __restrict__ pair_i, int* __restrict__ pair_j,
    float* __restrict__ pair_d, float* __restrict__ pair_dx,
    float* __restrict__ pair_dy, float* __restrict__ pair_dz,
    int* __restrict__ npairs_ctr,
    float* __restrict__ m, float* __restrict__ f_acc)
{
    __shared__ int   nj[MAXN];
    __shared__ float nd[MAXN], ndx[MAXN], ndy[MAXN], ndz[MAXN];
    __shared__ int cnt_s, base_s;
    int i = blockIdx.x, t = threadIdx.x;
    if (t == 0) cnt_s = 0;
    __syncthreads();
    float qx = q[i*3], qy = q[i*3+1], qz = q[i*3+2];
    for (int j = t; j < N_ATOMS; j += 256) {
        if (j == i) continue;
        float dx = qx - q[j*3], dy = qy - q[j*3+1], dz = qz - q[j*3+2];
        float d2 = dx*dx + dy*dy + dz*dz;
        if (d2 < CUT2) {
            int p = atomicAdd(&cnt_s, 1);
            if (p < MAXN) { nj[p] = j; nd[p] = sqrtf(d2);
                            ndx[p] = dx; ndy[p] = dy; ndz[p] = dz; }
        }
    }
    int g = i * 256 + t;                         // 196608 global ids
    if (g < N_ATOMS * FD) { h[g] = embed[z[g >> 7] * FD + (g & 127)]; m[g] = 0.f; }
    int g2 = g - N_ATOMS * FD;
    if (g2 >= 0 && g2 < FD * FD) {
        int r = g2 >> 7, c = g2 & 127;
        float w = W2[g2];
        W2T[c * FD + r] = w;
        W3T[c * FD + r] = W3[g2];
        unsigned short hb = f2bf(w);
        w2bh[c * FD + r] = hb;                   // [c][k] layout, k contiguous
        w2bl[c * FD + r] = f2bf(w - bf2f(hb));
    }
    if (g < 3 * N_ATOMS) f_acc[g] = 0.f;
    __syncthreads();
    if (t == 0) base_s = atomicAdd(npairs_ctr, min(cnt_s, MAXN));
    __syncthreads();
    int cnt = min(cnt_s, MAXN), base = base_s;
    if (t < cnt) {
        pair_i[base+t] = i;      pair_j[base+t] = nj[t];
        pair_d[base+t] = nd[t];  pair_dx[base+t] = ndx[t];
        pair_dy[base+t] = ndy[t]; pair_dz[base+t] = ndz[t];
    }
}

// ---------------------------------------------------------------- fwd (PPF=32)
// R16 three-phase register-diet structure (best known).
__global__ __launch_bounds__(256) void fwd_kernel(
    const float* __restrict__ W1, const float* __restrict__ b1,
    const float* __restrict__ W2, const float* __restrict__ b2,
    const float* __restrict__ h,
    const int* __restrict__ pair_i, const int* __restrict__ pair_j,
    const float* __restrict__ pair_d, const int* __restrict__ npairs_ctr,
    float* __restrict__ m)
{
    __shared__ float rbf_s[PPF * RST];    //  4608 B
    __shared__ float a1_s[PPF * AST];     // 16896 B
    __shared__ float filt_s[PPF * AST];   // 16896 B
    __shared__ int   pis[PPF], pjs[PPF];  //   256 B  (total ~38.7 KB)
    int t = threadIdx.x;
    int base = blockIdx.x * PPF;
    int np = npairs_ctr[0];
    if (base >= np) return;

    if (t < PPF) {
        int p = base + t; bool ok = p < np;
        pis[t] = ok ? pair_i[p] : 0;
        pjs[t] = ok ? pair_j[p] : 0;
    }
    for (int idx = t; idx < PPF * NRBF; idx += 256) {
        int p = idx >> 5, k = idx & 31;
        int gp = base + p;
        float d = (gp < np) ? pair_d[gp] : 1.0f;
        float u = d - CSTEP * (float)k;
        rbf_s[p * RST + k] = __expf(-GAMMA_ * u * u);
    }
    __syncthreads();

    // Phase A: a1[p][c] = relu(b1[c] + rbf[p]@W1[:,c]); thread = (c, 16-pair half)
    {
        int c = t & 127, ph = t >> 7;
        float w1c[NRBF];
#pragma unroll
        for (int k = 0; k < NRBF; k++) w1c[k] = W1[k * FD + c];
        float b1c = b1[c];
        for (int p = ph * 16; p < ph * 16 + 16; p++) {
            float u = b1c;
#pragma unroll
            for (int k4 = 0; k4 < NRBF / 4; k4++) {
                float4 r = *(const float4*)(rbf_s + p * RST + k4 * 4);
                u += r.x*w1c[k4*4] + r.y*w1c[k4*4+1] + r.z*w1c[k4*4+2] + r.w*w1c[k4*4+3];
            }
            a1_s[p * AST + c] = fmaxf(u, 0.f);
        }
    }
    __syncthreads();

    // Phase B: filt[p][c4..] = a1[p] @ W2[:,c4..]  (raw; b2 added in phase C)
    {
        int st = t >> 5, cg = t & 31, c4 = 4 * cg;
        float acc[4][4];
#pragma unroll
        for (int e = 0; e < 4; e++) { acc[e][0]=0; acc[e][1]=0; acc[e][2]=0; acc[e][3]=0; }
        for (int k = 0; k < FD; k += 4) {
            float4 w0 = *(const float4*)(W2 + (k+0) * FD + c4);
            float4 w1v= *(const float4*)(W2 + (k+1) * FD + c4);
            float4 w2v= *(const float4*)(W2 + (k+2) * FD + c4);
            float4 w3v= *(const float4*)(W2 + (k+3) * FD + c4);
#pragma unroll
            for (int e = 0; e < 4; e++) {
                float4 a = *(const float4*)(a1_s + (st*4+e) * AST + k);
                acc[e][0] += a.x*w0.x + a.y*w1v.x + a.z*w2v.x + a.w*w3v.x;
                acc[e][1] += a.x*w0.y + a.y*w1v.y + a.z*w2v.y + a.w*w3v.y;
                acc[e][2] += a.x*w0.z + a.y*w1v.z + a.z*w2v.z + a.w*w3v.z;
                acc[e][3] += a.x*w0.w + a.y*w1v.w + a.z*w2v.w + a.w*w3v.w;
            }
        }
#pragma unroll
        for (int e = 0; e < 4; e++) {
            float4 fv; fv.x = acc[e][0]; fv.y = acc[e][1];
            fv.z = acc[e][2]; fv.w = acc[e][3];
            *(float4*)(filt_s + (st*4+e) * AST + c4) = fv;
        }
    }
    __syncthreads();

    // Phase C: m[i,c] += (filt[p][c]+b2[c]) * h[j_p][c]; thread = (c, half)
    {
        int c = t & 127, ph = t >> 7;
        float b2c = b2[c];
        float r = 0.f;
        int p0 = ph * 16;
        int cur_i = pis[p0];
        for (int p = p0; p < p0 + 16; p++) {
            int ip = pis[p];
            if (ip != cur_i) {
                atomicAdd(m + cur_i * FD + c, r);
                r = 0.f; cur_i = ip;
            }
            if (base + p < np)
                r += (filt_s[p * AST + c] + b2c) * h[pjs[p] * FD + c];
        }
        atomicAdd(m + cur_i * FD + c, r);
    }
}

// ---------------------------------------------------------------- mbar (R20)
__global__ __launch_bounds__(256) void mbar_kernel(
    const float* __restrict__ m, const float* __restrict__ W3,
    const float* __restrict__ W3T, const float* __restrict__ wout,
    float* __restrict__ mbar)
{
    __shared__ float mrow[FD];
    __shared__ float gb[FD];
    __shared__ float part[256];
    int i = blockIdx.x, t = threadIdx.x;
    if (t < FD) mrow[t] = m[i * FD + t];
    __syncthreads();
    int c = t & 127, hh = t >> 7;          // hh = 0/1 -> f half
    int f0 = hh * 64;
    float g = 0.f;
#pragma unroll 8
    for (int f = f0; f < f0 + 64; f++) g += mrow[f] * W3[f * FD + c];
    part[t] = g;
    __syncthreads();
    if (t < FD) gb[t] = (part[t] + part[t + 128] > 0.f) ? wout[t] : 0.f;
    __syncthreads();
    float mb = 0.f;
#pragma unroll 8
    for (int f = f0; f < f0 + 64; f++) mb += gb[f] * W3T[f * FD + c];
    part[t] = mb;
    __syncthreads();
    if (t < FD) mbar[i * FD + t] = part[t] + part[t + 128];
}

// ---------------------------------------------------------------- bwd (PPBW=32, MFMA)
// R22: stage -> {ts-fill(bf16 hi/lo) + gef(f32)} -> MFMA GEMM (split) ->
// gef-fold + 16-lane shuffle reduce -> per-pair scatter. 3 barriers.
__global__ __launch_bounds__(256) void bwd_kernel(
    const float* __restrict__ W1, const float* __restrict__ b1,
    const unsigned short* __restrict__ w2bh, const unsigned short* __restrict__ w2bl,
    const float* __restrict__ h, const float* __restrict__ mbar,
    const int* __restrict__ pair_i, const int* __restrict__ pair_j,
    const float* __restrict__ pair_d, const float* __restrict__ pair_dx,
    const float* __restrict__ pair_dy, const float* __restrict__ pair_dz,
    const int* __restrict__ npairs_ctr, float* __restrict__ f_acc)
{
    __shared__ float rbf_s[PPBW * RST];        //  4608 B
    __shared__ float crbf_s[PPBW * RST];       //  4608 B
    __shared__ float gef[PPBW * AST];          // 16896 B
    __shared__ unsigned short ts_h[PPBW * TST]; // 8704 B
    __shared__ unsigned short ts_l[PPBW * TST]; // 8704 B
    __shared__ float sred[4 * PPBW];           //   512 B
    __shared__ int   pis[PPBW], pjs[PPBW];     //   256 B (total ~44.3 KB)
    int t = threadIdx.x;
    int base = blockIdx.x * PPBW;
    int np = npairs_ctr[0];
    if (base >= np) return;

    if (t < PPBW) {
        int p = base + t; bool ok = p < np;
        pis[t] = ok ? pair_i[p] : 0;
        pjs[t] = ok ? pair_j[p] : 0;
    }
    for (int idx = t; idx < PPBW * NRBF; idx += 256) {
        int p = idx >> 5, k = idx & 31;
        int gp = base + p;
        float d = (gp < np) ? pair_d[gp] : 1.0f;
        float u = d - CSTEP * (float)k;
        float r = __expf(-GAMMA_ * u * u);
        rbf_s[p * RST + k]  = r;
        crbf_s[p * RST + k] = -2.f * GAMMA_ * u * r;
    }
    __syncthreads();                       // pis/pjs + rbf/crbf ready

    // ts-fill: ts[p][c] = mbar[i_p][c] * h[j_p][c] -> bf16 hi/lo in LDS
    for (int idx = t; idx < PPBW * 32; idx += 256) {
        int p = idx >> 5, c4g = (idx & 31) * 4;
        float4 mb4 = *(const float4*)(mbar + pis[p] * FD + c4g);
        float4 hj4 = *(const float4*)(h    + pjs[p] * FD + c4g);
        float v0 = mb4.x*hj4.x, v1 = mb4.y*hj4.y, v2 = mb4.z*hj4.z, v3 = mb4.w*hj4.w;
        ushort4 hv, lv;
        hv.x = f2bf(v0); lv.x = f2bf(v0 - bf2f(hv.x));
        hv.y = f2bf(v1); lv.y = f2bf(v1 - bf2f(hv.y));
        hv.z = f2bf(v2); lv.z = f2bf(v2 - bf2f(hv.z));
        hv.w = f2bf(v3); lv.w = f2bf(v3 - bf2f(hv.w));
        *(ushort4*)(ts_h + p * TST + c4g) = hv;
        *(ushort4*)(ts_l + p * TST + c4g) = lv;
    }

    // gef phase: thread = (c, 16-pair half); w1c regs die at phase end
    {
        int c = t & 127, ph = t >> 7;
        float w1c[NRBF];
#pragma unroll
        for (int k = 0; k < NRBF; k++) w1c[k] = W1[k * FD + c];
        float b1c = b1[c];
        for (int p = ph * 16; p < ph * 16 + 16; p++) {
            float u1 = b1c, ef = 0.f;
#pragma unroll
            for (int k4 = 0; k4 < NRBF / 4; k4++) {
                float4 r = *(const float4*)(rbf_s  + p * RST + k4 * 4);
                float4 cd= *(const float4*)(crbf_s + p * RST + k4 * 4);
                u1 += r.x*w1c[k4*4] + r.y*w1c[k4*4+1] + r.z*w1c[k4*4+2] + r.w*w1c[k4*4+3];
                ef += cd.x*w1c[k4*4] + cd.y*w1c[k4*4+1] + cd.z*w1c[k4*4+2] + cd.w*w1c[k4*4+3];
            }
            gef[p * AST + c] = (u1 > 0.f) ? ef : 0.f;
        }
    }
    __syncthreads();                       // ts_h/ts_l + gef ready

    // MFMA GEMM: du1 = ts @ W2T  (M=32 -> 2 mtiles, N=128 -> 8 ntiles over
    // 4 waves, K=128 -> 4 ksteps). Split product: AhBh + AhBl + AlBh.
    {
        int wid = t >> 6, lane = t & 63;
        int lr = lane & 15;                // A-row / B-col selector
        int lg = lane >> 4;                // k-group (8 consecutive k)
        int c0 = (2 * wid + 0) * 16 + lr;  // this wave's two col-tiles
        int c1 = (2 * wid + 1) * 16 + lr;
        f32x4 acc00 = {0.f,0.f,0.f,0.f}, acc01 = {0.f,0.f,0.f,0.f};
        f32x4 acc10 = {0.f,0.f,0.f,0.f}, acc11 = {0.f,0.f,0.f,0.f};
#pragma unroll
        for (int ks = 0; ks < 4; ks++) {
            int kb = ks * 32 + lg * 8;
            short8v ah0 = *(const short8v*)(ts_h + (lr     ) * TST + kb);
            short8v ah1 = *(const short8v*)(ts_h + (16 + lr) * TST + kb);
            short8v al0 = *(const short8v*)(ts_l + (lr     ) * TST + kb);
            short8v al1 = *(const short8v*)(ts_l + (16 + lr) * TST + kb);
            short8v bh0 = *(const short8v*)(w2bh + c0 * FD + kb);
            short8v bh1 = *(const short8v*)(w2bh + c1 * FD + kb);
            short8v bl0 = *(const short8v*)(w2bl + c0 * FD + kb);
            short8v bl1 = *(const short8v*)(w2bl + c1 * FD + kb);
            acc00 = __builtin_amdgcn_mfma_f32_16x16x32_bf16(ah0, bh0, acc00, 0, 0, 0);
            acc01 = __builtin_amdgcn_mfma_f32_16x16x32_bf16(ah0, bh1, acc01, 0, 0, 0);
            acc10 = __builtin_amdgcn_mfma_f32_16x16x32_bf16(ah1, bh0, acc10, 0, 0, 0);
            acc11 = __builtin_amdgcn_mfma_f32_16x16x32_bf16(ah1, bh1, acc11, 0, 0, 0);
            acc00 = __builtin_amdgcn_mfma_f32_16x16x32_bf16(ah0, bl0, acc00, 0, 0, 0);
            acc01 = __builtin_amdgcn_mfma_f32_16x16x32_bf16(ah0, bl1, acc01, 0, 0, 0);
            acc10 = __builtin_amdgcn_mfma_f32_16x16x32_bf16(ah1, bl0, acc10, 0, 0, 0);
            acc11 = __builtin_amdgcn_mfma_f32_16x16x32_bf16(ah1, bl1, acc11, 0, 0, 0);
            acc00 = __builtin_amdgcn_mfma_f32_16x16x32_bf16(al0, bh0, acc00, 0, 0, 0);
            acc01 = __builtin_amdgcn_mfma_f32_16x16x32_bf16(al0, bh1, acc01, 0, 0, 0);
            acc10 = __builtin_amdgcn_mfma_f32_16x16x32_bf16(al1, bh0, acc10, 0, 0, 0);
            acc11 = __builtin_amdgcn_mfma_f32_16x16x32_bf16(al1, bh1, acc11, 0, 0, 0);
        }
        // Epilogue: fold gef, reduce over cols. C/D: col=lane&15,
        // row = (lane>>4)*4 + reg  [verified layout].
        float part[8];
#pragma unroll
        for (int r = 0; r < 4; r++) {
            int pA = lg * 4 + r;           // mtile 0
            int pB = 16 + lg * 4 + r;      // mtile 1
            part[r]     = acc00[r] * gef[pA * AST + c0] + acc01[r] * gef[pA * AST + c1];
            part[4 + r] = acc10[r] * gef[pB * AST + c0] + acc11[r] * gef[pB * AST + c1];
        }
#pragma unroll
        for (int mask = 1; mask < 16; mask <<= 1) {
#pragma unroll
            for (int e = 0; e < 8; e++) part[e] += __shfl_xor(part[e], mask, 64);
        }
        if (lr == 0) {
#pragma unroll
            for (int r = 0; r < 4; r++) {
                sred[wid * PPBW + lg * 4 + r]      = part[r];
                sred[wid * PPBW + 16 + lg * 4 + r] = part[4 + r];
            }
        }
    }
    __syncthreads();

    // Final per-pair scatter (32 pairs by threads 0..31)
    if (t < PPBW) {
        int gp = base + t;
        if (gp < np) {
            float s = sred[t] + sred[PPBW + t] + sred[2*PPBW + t] + sred[3*PPBW + t];
            int ii = pis[t], jj = pjs[t];
            float coef = s / pair_d[gp];
            float fx = coef * pair_dx[gp];
            float fy = coef * pair_dy[gp];
            float fz = coef * pair_dz[gp];
            atomicAdd(f_acc + ii*3 + 0, -fx);
            atomicAdd(f_acc + ii*3 + 1, -fy);
            atomicAdd(f_acc + ii*3 + 2, -fz);
            atomicAdd(f_acc + jj*3 + 0, fx);
            atomicAdd(f_acc + jj*3 + 1, fy);
            atomicAdd(f_acc + jj*3 + 2, fz);
        }
    }
}

// ---------------------------------------------------------------- finalize
__global__ __launch_bounds__(256) void fin_kernel(
    const float* __restrict__ v, const float* __restrict__ mass,
    const float* __restrict__ p_eta, const float* __restrict__ f_acc,
    float* __restrict__ out)
{
    __shared__ float red[256];
    int t = threadIdx.x;
    float ke = 0.f;
    float c = p_eta[0] / Q0_F;
    for (int idx = t; idx < 3 * N_ATOMS; idx += 256) {
        int a = idx / 3;
        float vv = v[idx], mi = mass[a];
        out[DVDT_OFF + idx] = (f_acc[idx] - c * vv * mi) / mi;
        out[V_OFF + idx] = vv;
        ke += 0.5f * mi * vv * vv;
    }
    red[t] = ke;
    __syncthreads();
    for (int s = 128; s > 0; s >>= 1) {
        if (t < s) red[t] += red[t + s];
        __syncthreads();
    }
    if (t == 0) {
        float k0 = red[0];
        float e0 = p_eta[0], e1 = p_eta[1], e2 = p_eta[2], e3 = p_eta[3];
        out[PETA_OFF + 0] = 2.f * (k0 - TARGET_KE) - e0 * e1 / QI_F;
        out[PETA_OFF + 1] = e0 * e0 / Q0_F - KT_F - e1 * e2 / QI_F;
        out[PETA_OFF + 2] = e1 * e1 / QI_F - KT_F - e2 * e3 / QI_F;
        out[PETA_OFF + 3] = e2 * e2 / QI_F - KT_F;
    }
}

// ---------------------------------------------------------------- launch
extern "C" void kernel_launch(void* const* d_in, const int* in_sizes, int n_in,
                              void* d_out, int out_size, void* d_ws, size_t ws_size,
                              hipStream_t stream)
{
    const float* v     = (const float*)d_in[0];
    const float* q     = (const float*)d_in[1];
    const float* p_eta = (const float*)d_in[2];
    const float* mass  = (const float*)d_in[3];
    const float* embed = (const float*)d_in[4];
    const float* W1    = (const float*)d_in[5];
    const float* b1    = (const float*)d_in[6];
    const float* W2    = (const float*)d_in[7];
    const float* b2    = (const float*)d_in[8];
    const float* W3    = (const float*)d_in[9];
    const float* wout  = (const float*)d_in[10];
    const int*   z     = (const int*)d_in[11];
    float* out = (float*)d_out;

    float* h     = (float*)d_ws;
    float* W2T   = h + N_ATOMS * FD;
    float* W3T   = W2T + FD * FD;
    float* m     = W3T + FD * FD;
    float* f_acc = m + N_ATOMS * FD;
    float* pair_d  = f_acc + 3 * N_ATOMS;
    float* pair_dx = pair_d + N_ATOMS * MAXN;
    float* pair_dy = pair_dx + N_ATOMS * MAXN;
    float* pair_dz = pair_dy + N_ATOMS * MAXN;
    int* pair_i = (int*)(pair_dz + N_ATOMS * MAXN);
    int* pair_j = pair_i + N_ATOMS * MAXN;
    int* npairs_ctr = pair_j + N_ATOMS * MAXN;
    float* mbar  = (float*)(npairs_ctr + 64);     // 64-int pad for alignment
    unsigned short* w2bh = (unsigned short*)(mbar + N_ATOMS * FD);
    unsigned short* w2bl = w2bh + FD * FD;

    hipMemsetAsync(npairs_ctr, 0, sizeof(int), stream);

    prep_kernel<<<N_ATOMS, 256, 0, stream>>>(q, z, embed, W2, W3, h, W2T, W3T,
                                             w2bh, w2bl,
                                             pair_i, pair_j, pair_d,
                                             pair_dx, pair_dy, pair_dz,
                                             npairs_ctr, m, f_acc);
    fwd_kernel<<<FTILES, 256, 0, stream>>>(W1, b1, W2, b2, h, pair_i,
                                           pair_j, pair_d, npairs_ctr, m);
    mbar_kernel<<<N_ATOMS, 256, 0, stream>>>(m, W3, W3T, wout, mbar);
    bwd_kernel<<<BTILES, 256, 0, stream>>>(W1, b1, w2bh, w2bl, h, mbar,
                                           pair_i, pair_j, pair_d, pair_dx,
                                           pair_dy, pair_dz, npairs_ctr, f_acc);
    fin_kernel<<<1, 256, 0, stream>>>(v, mass, p_eta, f_acc, out);
}

// Round 6
// 152.552 us; speedup vs baseline: 1.1727x; 1.0237x over previous
//
#include <hip/hip_runtime.h>
#include <math.h>

// Problem constants (match reference)
#define N_ATOMS 768
#define FD 128          // feature width
#define NRBF 32
#define MAXN 64         // per-atom neighbor cap (mean ~26)
#define PPF 32          // fwd: pairs per block (2 M-tiles of 16)
#define PPBW 32         // bwd: pairs per block (2 M-tiles of 16)
#define FTILES (N_ATOMS * MAXN / PPF)     // 1536
#define BTILES (N_ATOMS * MAXN / PPBW)    // 1536
#define AST 132         // padded LDS stride for [*][128] f32 tiles
#define RST 36          // padded LDS stride for [*][32] rbf tiles
#define TST 136         // padded LDS stride for [*][128] bf16 (ushort) tiles

constexpr float  CUT2   = 25.0f;
constexpr float  GAMMA_ = 40.96f;            // 1/(5/32)^2
constexpr float  CSTEP  = 5.0f / 31.0f;      // linspace(0,5,32) step
constexpr double KB_D   = 8.617330337217213e-05;
constexpr double KT_D   = 300.0 * KB_D;
constexpr float  KT_F   = (float)KT_D;
constexpr float  TARGET_KE = (float)(0.5 * 2304.0 * KT_D);
constexpr float  Q0_F   = (float)(2.0 * 2304.0 * KT_D * 400.0);  // Q[0]
constexpr float  QI_F   = (float)(2.0 * KT_D * 400.0);           // Q[1..3]

#define DVDT_OFF 0
#define V_OFF    (3 * N_ATOMS)
#define PETA_OFF (6 * N_ATOMS)

using short8v = __attribute__((ext_vector_type(8))) short;
using f32x4   = __attribute__((ext_vector_type(4))) float;

__device__ __forceinline__ unsigned short f2bf(float x) {
    unsigned int u = __float_as_uint(x);
    u += 0x7FFF + ((u >> 16) & 1);           // round-to-nearest-even
    return (unsigned short)(u >> 16);
}
__device__ __forceinline__ float bf2f(unsigned short h) {
    return __uint_as_float(((unsigned int)h) << 16);
}

// Hard-won rules (22 rounds of counters):
// 1. NO __launch_bounds__ min-wave hints on GEMM kernels (spill cliff).
// 2. Reduce register demand STRUCTURALLY — phase-split through LDS.
// 3. NEVER put __threadfence / completion counters on the hot grid (R14).
// 4. R18 FAILED: per-wave mbar spread doesn't shorten chains (nda~1.6 < 4).
// 5. R19 FAILED: LDS weight staging — redundant weight stream is L1-absorbed.
// 6. R20 WIN: mbar extracted to own 768-block kernel (bwd 56->45.7).
// 7. R21 NEUTRAL: PPBW 16->32. Vector GEMM is in-phase-L2-latency bound;
//    tiling knobs don't move it.
// 8. R22 WIN+BUG: MFMA split-bf16 bwd GEMM -> bwd <39us, BUT prep wrote
//    B transposed (computed ts@W2 not ts@W2T) -> absmax 0.826 (passed only
//    by threshold luck). bwd B-operand must be bf16(W2) NATIVE layout
//    (B[k][c']=W2T[k][c']=W2[c'][k] -> w2b[c'][k]).
// 9. R23: fix w2b layout; port MFMA to fwd phase B (B[k][c]=W2[k][c] ->
//    w2f[c][k]=W2[k][c], the transposed layout). relu gates stay fp32
//    (a1 rounded AFTER the gate -> no gate-flip risk).

// ---------------------------------------------------------------- prep
__global__ __launch_bounds__(256) void prep_kernel(
    const float* __restrict__ q, const int* __restrict__ z,
    const float* __restrict__ embed, const float* __restrict__ W2,
    const float* __restrict__ W3,
    float* __restrict__ h, float* __restrict__ W3T,
    unsigned short* __restrict__ w2fh, unsigned short* __restrict__ w2fl,
    unsigned short* __restrict__ w2bh, unsigned short* __restrict__ w2bl,
    int* __restrict__ pair_i, int* __restrict__ pair_j,
    float* __restrict__ pair_d, float* __restrict__ pair_dx,
    float* __restrict__ pair_dy, float* __restrict__ pair_dz,
    int* __restrict__ npairs_ctr,
    float* __restrict__ m, float* __restrict__ f_acc)
{
    __shared__ int   nj[MAXN];
    __shared__ float nd[MAXN], ndx[MAXN], ndy[MAXN], ndz[MAXN];
    __shared__ int cnt_s, base_s;
    int i = blockIdx.x, t = threadIdx.x;
    if (t == 0) cnt_s = 0;
    __syncthreads();
    float qx = q[i*3], qy = q[i*3+1], qz = q[i*3+2];
    for (int j = t; j < N_ATOMS; j += 256) {
        if (j == i) continue;
        float dx = qx - q[j*3], dy = qy - q[j*3+1], dz = qz - q[j*3+2];
        float d2 = dx*dx + dy*dy + dz*dz;
        if (d2 < CUT2) {
            int p = atomicAdd(&cnt_s, 1);
            if (p < MAXN) { nj[p] = j; nd[p] = sqrtf(d2);
                            ndx[p] = dx; ndy[p] = dy; ndz[p] = dz; }
        }
    }
    int g = i * 256 + t;                         // 196608 global ids
    if (g < N_ATOMS * FD) { h[g] = embed[z[g >> 7] * FD + (g & 127)]; m[g] = 0.f; }
    int g2 = g - N_ATOMS * FD;
    if (g2 >= 0 && g2 < FD * FD) {
        int r = g2 >> 7, c = g2 & 127;
        float w = W2[g2];                        // W2[r][c]
        unsigned short hb = f2bf(w);
        unsigned short lb = f2bf(w - bf2f(hb));
        w2bh[g2] = hb;                           // bwd B: w2b[c'][k]=W2[c'][k]
        w2bl[g2] = lb;                           //   (native layout)
        w2fh[c * FD + r] = hb;                   // fwd B: w2f[c][k]=W2[k][c]
        w2fl[c * FD + r] = lb;                   //   (transposed layout)
        W3T[c * FD + r] = W3[g2];
    }
    if (g < 3 * N_ATOMS) f_acc[g] = 0.f;
    __syncthreads();
    if (t == 0) base_s = atomicAdd(npairs_ctr, min(cnt_s, MAXN));
    __syncthreads();
    int cnt = min(cnt_s, MAXN), base = base_s;
    if (t < cnt) {
        pair_i[base+t] = i;      pair_j[base+t] = nj[t];
        pair_d[base+t] = nd[t];  pair_dx[base+t] = ndx[t];
        pair_dy[base+t] = ndy[t]; pair_dz[base+t] = ndz[t];
    }
}

// ---------------------------------------------------------------- fwd (PPF=32, MFMA)
// R23: phase A (fp32 gate, bf16 hi/lo store) -> phase B MFMA split GEMM ->
// phase C (fp32, unchanged).
__global__ __launch_bounds__(256) void fwd_kernel(
    const float* __restrict__ W1, const float* __restrict__ b1,
    const unsigned short* __restrict__ w2fh, const unsigned short* __restrict__ w2fl,
    const float* __restrict__ b2, const float* __restrict__ h,
    const int* __restrict__ pair_i, const int* __restrict__ pair_j,
    const float* __restrict__ pair_d, const int* __restrict__ npairs_ctr,
    float* __restrict__ m)
{
    __shared__ float rbf_s[PPF * RST];          //  4608 B
    __shared__ unsigned short a1h[PPF * TST];   //  8704 B
    __shared__ unsigned short a1l[PPF * TST];   //  8704 B
    __shared__ float filt_s[PPF * AST];         // 16896 B
    __shared__ int   pis[PPF], pjs[PPF];        //   256 B (total ~39.2 KB)
    int t = threadIdx.x;
    int base = blockIdx.x * PPF;
    int np = npairs_ctr[0];
    if (base >= np) return;

    if (t < PPF) {
        int p = base + t; bool ok = p < np;
        pis[t] = ok ? pair_i[p] : 0;
        pjs[t] = ok ? pair_j[p] : 0;
    }
    for (int idx = t; idx < PPF * NRBF; idx += 256) {
        int p = idx >> 5, k = idx & 31;
        int gp = base + p;
        float d = (gp < np) ? pair_d[gp] : 1.0f;
        float u = d - CSTEP * (float)k;
        rbf_s[p * RST + k] = __expf(-GAMMA_ * u * u);
    }
    __syncthreads();

    // Phase A: a1[p][c] = relu(b1[c] + rbf[p]@W1[:,c]) -> bf16 hi/lo.
    // Gate decided in fp32; rounding applied after.
    {
        int c = t & 127, ph = t >> 7;
        float w1c[NRBF];
#pragma unroll
        for (int k = 0; k < NRBF; k++) w1c[k] = W1[k * FD + c];
        float b1c = b1[c];
        for (int p = ph * 16; p < ph * 16 + 16; p++) {
            float u = b1c;
#pragma unroll
            for (int k4 = 0; k4 < NRBF / 4; k4++) {
                float4 r = *(const float4*)(rbf_s + p * RST + k4 * 4);
                u += r.x*w1c[k4*4] + r.y*w1c[k4*4+1] + r.z*w1c[k4*4+2] + r.w*w1c[k4*4+3];
            }
            u = fmaxf(u, 0.f);
            unsigned short hb = f2bf(u);
            a1h[p * TST + c] = hb;
            a1l[p * TST + c] = f2bf(u - bf2f(hb));
        }
    }
    __syncthreads();

    // Phase B: filt = a1 @ W2 via MFMA (M=32: 2 mtiles, N=128: 2 col-tiles
    // per wave, K=128: 4 ksteps; split AhBh+AhBl+AlBh).
    {
        int wid = t >> 6, lane = t & 63;
        int lr = lane & 15;                // A-row / B-col selector
        int lg = lane >> 4;                // k-group (8 consecutive k)
        int c0 = (2 * wid + 0) * 16 + lr;
        int c1 = (2 * wid + 1) * 16 + lr;
        f32x4 acc00 = {0.f,0.f,0.f,0.f}, acc01 = {0.f,0.f,0.f,0.f};
        f32x4 acc10 = {0.f,0.f,0.f,0.f}, acc11 = {0.f,0.f,0.f,0.f};
#pragma unroll
        for (int ks = 0; ks < 4; ks++) {
            int kb = ks * 32 + lg * 8;
            short8v ah0 = *(const short8v*)(a1h + (lr     ) * TST + kb);
            short8v ah1 = *(const short8v*)(a1h + (16 + lr) * TST + kb);
            short8v al0 = *(const short8v*)(a1l + (lr     ) * TST + kb);
            short8v al1 = *(const short8v*)(a1l + (16 + lr) * TST + kb);
            short8v bh0 = *(const short8v*)(w2fh + c0 * FD + kb);
            short8v bh1 = *(const short8v*)(w2fh + c1 * FD + kb);
            short8v bl0 = *(const short8v*)(w2fl + c0 * FD + kb);
            short8v bl1 = *(const short8v*)(w2fl + c1 * FD + kb);
            acc00 = __builtin_amdgcn_mfma_f32_16x16x32_bf16(ah0, bh0, acc00, 0, 0, 0);
            acc01 = __builtin_amdgcn_mfma_f32_16x16x32_bf16(ah0, bh1, acc01, 0, 0, 0);
            acc10 = __builtin_amdgcn_mfma_f32_16x16x32_bf16(ah1, bh0, acc10, 0, 0, 0);
            acc11 = __builtin_amdgcn_mfma_f32_16x16x32_bf16(ah1, bh1, acc11, 0, 0, 0);
            acc00 = __builtin_amdgcn_mfma_f32_16x16x32_bf16(ah0, bl0, acc00, 0, 0, 0);
            acc01 = __builtin_amdgcn_mfma_f32_16x16x32_bf16(ah0, bl1, acc01, 0, 0, 0);
            acc10 = __builtin_amdgcn_mfma_f32_16x16x32_bf16(ah1, bl0, acc10, 0, 0, 0);
            acc11 = __builtin_amdgcn_mfma_f32_16x16x32_bf16(ah1, bl1, acc11, 0, 0, 0);
            acc00 = __builtin_amdgcn_mfma_f32_16x16x32_bf16(al0, bh0, acc00, 0, 0, 0);
            acc01 = __builtin_amdgcn_mfma_f32_16x16x32_bf16(al0, bh1, acc01, 0, 0, 0);
            acc10 = __builtin_amdgcn_mfma_f32_16x16x32_bf16(al1, bh0, acc10, 0, 0, 0);
            acc11 = __builtin_amdgcn_mfma_f32_16x16x32_bf16(al1, bh1, acc11, 0, 0, 0);
        }
        // C/D layout: col=lane&15, row=(lane>>4)*4+reg  [verified].
#pragma unroll
        for (int r = 0; r < 4; r++) {
            int pA = lg * 4 + r, pB = 16 + lg * 4 + r;
            filt_s[pA * AST + c0] = acc00[r];
            filt_s[pA * AST + c1] = acc01[r];
            filt_s[pB * AST + c0] = acc10[r];
            filt_s[pB * AST + c1] = acc11[r];
        }
    }
    __syncthreads();

    // Phase C: m[i,c] += (filt[p][c]+b2[c]) * h[j_p][c]; thread = (c, half)
    {
        int c = t & 127, ph = t >> 7;
        float b2c = b2[c];
        float r = 0.f;
        int p0 = ph * 16;
        int cur_i = pis[p0];
        for (int p = p0; p < p0 + 16; p++) {
            int ip = pis[p];
            if (ip != cur_i) {
                atomicAdd(m + cur_i * FD + c, r);
                r = 0.f; cur_i = ip;
            }
            if (base + p < np)
                r += (filt_s[p * AST + c] + b2c) * h[pjs[p] * FD + c];
        }
        atomicAdd(m + cur_i * FD + c, r);
    }
}

// ---------------------------------------------------------------- mbar (R20)
__global__ __launch_bounds__(256) void mbar_kernel(
    const float* __restrict__ m, const float* __restrict__ W3,
    const float* __restrict__ W3T, const float* __restrict__ wout,
    float* __restrict__ mbar)
{
    __shared__ float mrow[FD];
    __shared__ float gb[FD];
    __shared__ float part[256];
    int i = blockIdx.x, t = threadIdx.x;
    if (t < FD) mrow[t] = m[i * FD + t];
    __syncthreads();
    int c = t & 127, hh = t >> 7;          // hh = 0/1 -> f half
    int f0 = hh * 64;
    float g = 0.f;
#pragma unroll 8
    for (int f = f0; f < f0 + 64; f++) g += mrow[f] * W3[f * FD + c];
    part[t] = g;
    __syncthreads();
    if (t < FD) gb[t] = (part[t] + part[t + 128] > 0.f) ? wout[t] : 0.f;
    __syncthreads();
    float mb = 0.f;
#pragma unroll 8
    for (int f = f0; f < f0 + 64; f++) mb += gb[f] * W3T[f * FD + c];
    part[t] = mb;
    __syncthreads();
    if (t < FD) mbar[i * FD + t] = part[t] + part[t + 128];
}

// ---------------------------------------------------------------- bwd (PPBW=32, MFMA)
// R22 structure (layout bug fixed via prep): stage -> {ts-fill bf16 hi/lo +
// gef f32} -> MFMA split GEMM -> gef-fold + shuffle reduce -> scatter.
__global__ __launch_bounds__(256) void bwd_kernel(
    const float* __restrict__ W1, const float* __restrict__ b1,
    const unsigned short* __restrict__ w2bh, const unsigned short* __restrict__ w2bl,
    const float* __restrict__ h, const float* __restrict__ mbar,
    const int* __restrict__ pair_i, const int* __restrict__ pair_j,
    const float* __restrict__ pair_d, const float* __restrict__ pair_dx,
    const float* __restrict__ pair_dy, const float* __restrict__ pair_dz,
    const int* __restrict__ npairs_ctr, float* __restrict__ f_acc)
{
    __shared__ float rbf_s[PPBW * RST];        //  4608 B
    __shared__ float crbf_s[PPBW * RST];       //  4608 B
    __shared__ float gef[PPBW * AST];          // 16896 B
    __shared__ unsigned short ts_h[PPBW * TST]; // 8704 B
    __shared__ unsigned short ts_l[PPBW * TST]; // 8704 B
    __shared__ float sred[4 * PPBW];           //   512 B
    __shared__ int   pis[PPBW], pjs[PPBW];     //   256 B (total ~44.3 KB)
    int t = threadIdx.x;
    int base = blockIdx.x * PPBW;
    int np = npairs_ctr[0];
    if (base >= np) return;

    if (t < PPBW) {
        int p = base + t; bool ok = p < np;
        pis[t] = ok ? pair_i[p] : 0;
        pjs[t] = ok ? pair_j[p] : 0;
    }
    for (int idx = t; idx < PPBW * NRBF; idx += 256) {
        int p = idx >> 5, k = idx & 31;
        int gp = base + p;
        float d = (gp < np) ? pair_d[gp] : 1.0f;
        float u = d - CSTEP * (float)k;
        float r = __expf(-GAMMA_ * u * u);
        rbf_s[p * RST + k]  = r;
        crbf_s[p * RST + k] = -2.f * GAMMA_ * u * r;
    }
    __syncthreads();                       // pis/pjs + rbf/crbf ready

    // ts-fill: ts[p][c] = mbar[i_p][c] * h[j_p][c] -> bf16 hi/lo in LDS
    for (int idx = t; idx < PPBW * 32; idx += 256) {
        int p = idx >> 5, c4g = (idx & 31) * 4;
        float4 mb4 = *(const float4*)(mbar + pis[p] * FD + c4g);
        float4 hj4 = *(const float4*)(h    + pjs[p] * FD + c4g);
        float v0 = mb4.x*hj4.x, v1 = mb4.y*hj4.y, v2 = mb4.z*hj4.z, v3 = mb4.w*hj4.w;
        ushort4 hv, lv;
        hv.x = f2bf(v0); lv.x = f2bf(v0 - bf2f(hv.x));
        hv.y = f2bf(v1); lv.y = f2bf(v1 - bf2f(hv.y));
        hv.z = f2bf(v2); lv.z = f2bf(v2 - bf2f(hv.z));
        hv.w = f2bf(v3); lv.w = f2bf(v3 - bf2f(hv.w));
        *(ushort4*)(ts_h + p * TST + c4g) = hv;
        *(ushort4*)(ts_l + p * TST + c4g) = lv;
    }

    // gef phase: thread = (c, 16-pair half); w1c regs die at phase end
    {
        int c = t & 127, ph = t >> 7;
        float w1c[NRBF];
#pragma unroll
        for (int k = 0; k < NRBF; k++) w1c[k] = W1[k * FD + c];
        float b1c = b1[c];
        for (int p = ph * 16; p < ph * 16 + 16; p++) {
            float u1 = b1c, ef = 0.f;
#pragma unroll
            for (int k4 = 0; k4 < NRBF / 4; k4++) {
                float4 r = *(const float4*)(rbf_s  + p * RST + k4 * 4);
                float4 cd= *(const float4*)(crbf_s + p * RST + k4 * 4);
                u1 += r.x*w1c[k4*4] + r.y*w1c[k4*4+1] + r.z*w1c[k4*4+2] + r.w*w1c[k4*4+3];
                ef += cd.x*w1c[k4*4] + cd.y*w1c[k4*4+1] + cd.z*w1c[k4*4+2] + cd.w*w1c[k4*4+3];
            }
            gef[p * AST + c] = (u1 > 0.f) ? ef : 0.f;
        }
    }
    __syncthreads();                       // ts_h/ts_l + gef ready

    // MFMA GEMM: du1 = ts @ W2T  (B[k][c']=W2[c'][k] from native-layout w2b).
    {
        int wid = t >> 6, lane = t & 63;
        int lr = lane & 15;                // A-row / B-col selector
        int lg = lane >> 4;                // k-group (8 consecutive k)
        int c0 = (2 * wid + 0) * 16 + lr;  // this wave's two col-tiles
        int c1 = (2 * wid + 1) * 16 + lr;
        f32x4 acc00 = {0.f,0.f,0.f,0.f}, acc01 = {0.f,0.f,0.f,0.f};
        f32x4 acc10 = {0.f,0.f,0.f,0.f}, acc11 = {0.f,0.f,0.f,0.f};
#pragma unroll
        for (int ks = 0; ks < 4; ks++) {
            int kb = ks * 32 + lg * 8;
            short8v ah0 = *(const short8v*)(ts_h + (lr     ) * TST + kb);
            short8v ah1 = *(const short8v*)(ts_h + (16 + lr) * TST + kb);
            short8v al0 = *(const short8v*)(ts_l + (lr     ) * TST + kb);
            short8v al1 = *(const short8v*)(ts_l + (16 + lr) * TST + kb);
            short8v bh0 = *(const short8v*)(w2bh + c0 * FD + kb);
            short8v bh1 = *(const short8v*)(w2bh + c1 * FD + kb);
            short8v bl0 = *(const short8v*)(w2bl + c0 * FD + kb);
            short8v bl1 = *(const short8v*)(w2bl + c1 * FD + kb);
            acc00 = __builtin_amdgcn_mfma_f32_16x16x32_bf16(ah0, bh0, acc00, 0, 0, 0);
            acc01 = __builtin_amdgcn_mfma_f32_16x16x32_bf16(ah0, bh1, acc01, 0, 0, 0);
            acc10 = __builtin_amdgcn_mfma_f32_16x16x32_bf16(ah1, bh0, acc10, 0, 0, 0);
            acc11 = __builtin_amdgcn_mfma_f32_16x16x32_bf16(ah1, bh1, acc11, 0, 0, 0);
            acc00 = __builtin_amdgcn_mfma_f32_16x16x32_bf16(ah0, bl0, acc00, 0, 0, 0);
            acc01 = __builtin_amdgcn_mfma_f32_16x16x32_bf16(ah0, bl1, acc01, 0, 0, 0);
            acc10 = __builtin_amdgcn_mfma_f32_16x16x32_bf16(ah1, bl0, acc10, 0, 0, 0);
            acc11 = __builtin_amdgcn_mfma_f32_16x16x32_bf16(ah1, bl1, acc11, 0, 0, 0);
            acc00 = __builtin_amdgcn_mfma_f32_16x16x32_bf16(al0, bh0, acc00, 0, 0, 0);
            acc01 = __builtin_amdgcn_mfma_f32_16x16x32_bf16(al0, bh1, acc01, 0, 0, 0);
            acc10 = __builtin_amdgcn_mfma_f32_16x16x32_bf16(al1, bh0, acc10, 0, 0, 0);
            acc11 = __builtin_amdgcn_mfma_f32_16x16x32_bf16(al1, bh1, acc11, 0, 0, 0);
        }
        // Epilogue: fold gef, reduce over cols. C/D: col=lane&15,
        // row=(lane>>4)*4+reg  [verified layout].
        float part[8];
#pragma unroll
        for (int r = 0; r < 4; r++) {
            int pA = lg * 4 + r;           // mtile 0
            int pB = 16 + lg * 4 + r;      // mtile 1
            part[r]     = acc00[r] * gef[pA * AST + c0] + acc01[r] * gef[pA * AST + c1];
            part[4 + r] = acc10[r] * gef[pB * AST + c0] + acc11[r] * gef[pB * AST + c1];
        }
#pragma unroll
        for (int mask = 1; mask < 16; mask <<= 1) {
#pragma unroll
            for (int e = 0; e < 8; e++) part[e] += __shfl_xor(part[e], mask, 64);
        }
        if (lr == 0) {
#pragma unroll
            for (int r = 0; r < 4; r++) {
                sred[wid * PPBW + lg * 4 + r]      = part[r];
                sred[wid * PPBW + 16 + lg * 4 + r] = part[4 + r];
            }
        }
    }
    __syncthreads();

    // Final per-pair scatter (32 pairs by threads 0..31)
    if (t < PPBW) {
        int gp = base + t;
        if (gp < np) {
            float s = sred[t] + sred[PPBW + t] + sred[2*PPBW + t] + sred[3*PPBW + t];
            int ii = pis[t], jj = pjs[t];
            float coef = s / pair_d[gp];
            float fx = coef * pair_dx[gp];
            float fy = coef * pair_dy[gp];
            float fz = coef * pair_dz[gp];
            atomicAdd(f_acc + ii*3 + 0, -fx);
            atomicAdd(f_acc + ii*3 + 1, -fy);
            atomicAdd(f_acc + ii*3 + 2, -fz);
            atomicAdd(f_acc + jj*3 + 0, fx);
            atomicAdd(f_acc + jj*3 + 1, fy);
            atomicAdd(f_acc + jj*3 + 2, fz);
        }
    }
}

// ---------------------------------------------------------------- finalize
__global__ __launch_bounds__(256) void fin_kernel(
    const float* __restrict__ v, const float* __restrict__ mass,
    const float* __restrict__ p_eta, const float* __restrict__ f_acc,
    float* __restrict__ out)
{
    __shared__ float red[256];
    int t = threadIdx.x;
    float ke = 0.f;
    float c = p_eta[0] / Q0_F;
    for (int idx = t; idx < 3 * N_ATOMS; idx += 256) {
        int a = idx / 3;
        float vv = v[idx], mi = mass[a];
        out[DVDT_OFF + idx] = (f_acc[idx] - c * vv * mi) / mi;
        out[V_OFF + idx] = vv;
        ke += 0.5f * mi * vv * vv;
    }
    red[t] = ke;
    __syncthreads();
    for (int s = 128; s > 0; s >>= 1) {
        if (t < s) red[t] += red[t + s];
        __syncthreads();
    }
    if (t == 0) {
        float k0 = red[0];
        float e0 = p_eta[0], e1 = p_eta[1], e2 = p_eta[2], e3 = p_eta[3];
        out[PETA_OFF + 0] = 2.f * (k0 - TARGET_KE) - e0 * e1 / QI_F;
        out[PETA_OFF + 1] = e0 * e0 / Q0_F - KT_F - e1 * e2 / QI_F;
        out[PETA_OFF + 2] = e1 * e1 / QI_F - KT_F - e2 * e3 / QI_F;
        out[PETA_OFF + 3] = e2 * e2 / QI_F - KT_F;
    }
}

// ---------------------------------------------------------------- launch
extern "C" void kernel_launch(void* const* d_in, const int* in_sizes, int n_in,
                              void* d_out, int out_size, void* d_ws, size_t ws_size,
                              hipStream_t stream)
{
    const float* v     = (const float*)d_in[0];
    const float* q     = (const float*)d_in[1];
    const float* p_eta = (const float*)d_in[2];
    const float* mass  = (const float*)d_in[3];
    const float* embed = (const float*)d_in[4];
    const float* W1    = (const float*)d_in[5];
    const float* b1    = (const float*)d_in[6];
    const float* W2    = (const float*)d_in[7];
    const float* b2    = (const float*)d_in[8];
    const float* W3    = (const float*)d_in[9];
    const float* wout  = (const float*)d_in[10];
    const int*   z     = (const int*)d_in[11];
    float* out = (float*)d_out;

    float* h     = (float*)d_ws;
    float* W2T_unused = h + N_ATOMS * FD;        // slot kept (layout stability)
    float* W3T   = W2T_unused + FD * FD;
    float* m     = W3T + FD * FD;
    float* f_acc = m + N_ATOMS * FD;
    float* pair_d  = f_acc + 3 * N_ATOMS;
    float* pair_dx = pair_d + N_ATOMS * MAXN;
    float* pair_dy = pair_dx + N_ATOMS * MAXN;
    float* pair_dz = pair_dy + N_ATOMS * MAXN;
    int* pair_i = (int*)(pair_dz + N_ATOMS * MAXN);
    int* pair_j = pair_i + N_ATOMS * MAXN;
    int* npairs_ctr = pair_j + N_ATOMS * MAXN;
    float* mbar  = (float*)(npairs_ctr + 64);     // 64-int pad for alignment
    unsigned short* w2bh = (unsigned short*)(mbar + N_ATOMS * FD);
    unsigned short* w2bl = w2bh + FD * FD;
    unsigned short* w2fh = w2bl + FD * FD;
    unsigned short* w2fl = w2fh + FD * FD;

    hipMemsetAsync(npairs_ctr, 0, sizeof(int), stream);

    prep_kernel<<<N_ATOMS, 256, 0, stream>>>(q, z, embed, W2, W3, h, W3T,
                                             w2fh, w2fl, w2bh, w2bl,
                                             pair_i, pair_j, pair_d,
                                             pair_dx, pair_dy, pair_dz,
                                             npairs_ctr, m, f_acc);
    fwd_kernel<<<FTILES, 256, 0, stream>>>(W1, b1, w2fh, w2fl, b2, h, pair_i,
                                           pair_j, pair_d, npairs_ctr, m);
    mbar_kernel<<<N_ATOMS, 256, 0, stream>>>(m, W3, W3T, wout, mbar);
    bwd_kernel<<<BTILES, 256, 0, stream>>>(W1, b1, w2bh, w2bl, h, mbar,
                                           pair_i, pair_j, pair_d, pair_dx,
                                           pair_dy, pair_dz, npairs_ctr, f_acc);
    fin_kernel<<<1, 256, 0, stream>>>(v, mass, p_eta, f_acc, out);
}

// Round 7
// 144.138 us; speedup vs baseline: 1.2412x; 1.0584x over previous
//
#include <hip/hip_runtime.h>
#include <math.h>

// Problem constants (match reference)
#define N_ATOMS 768
#define FD 128          // feature width
#define NRBF 32
#define MAXN 64         // per-atom neighbor cap (mean ~26)
#define PPF 32          // fwd: pairs per block (2 M-tiles of 16)
#define PPBW 32         // bwd: pairs per block (2 M-tiles of 16)
#define FTILES (N_ATOMS * MAXN / PPF)     // 1536
#define BTILES (N_ATOMS * MAXN / PPBW)    // 1536
#define AST 132         // padded LDS stride for [*][128] f32 tiles
#define TST 136         // padded LDS stride for [*][128] bf16 (ushort) tiles
#define RSTU 40         // padded ushort stride for [*][32] bf16 rbf tiles (80B, 16B-aligned)

constexpr float  CUT2   = 25.0f;
constexpr float  GAMMA_ = 40.96f;            // 1/(5/32)^2
constexpr float  CSTEP  = 5.0f / 31.0f;      // linspace(0,5,32) step
constexpr double KB_D   = 8.617330337217213e-05;
constexpr double KT_D   = 300.0 * KB_D;
constexpr float  KT_F   = (float)KT_D;
constexpr float  TARGET_KE = (float)(0.5 * 2304.0 * KT_D);
constexpr float  Q0_F   = (float)(2.0 * 2304.0 * KT_D * 400.0);  // Q[0]
constexpr float  QI_F   = (float)(2.0 * KT_D * 400.0);           // Q[1..3]

#define DVDT_OFF 0
#define V_OFF    (3 * N_ATOMS)
#define PETA_OFF (6 * N_ATOMS)

using short8v = __attribute__((ext_vector_type(8))) short;
using f32x4   = __attribute__((ext_vector_type(4))) float;

#define MFMA_B16 __builtin_amdgcn_mfma_f32_16x16x32_bf16

__device__ __forceinline__ unsigned short f2bf(float x) {
    unsigned int u = __float_as_uint(x);
    u += 0x7FFF + ((u >> 16) & 1);           // round-to-nearest-even
    return (unsigned short)(u >> 16);
}
__device__ __forceinline__ float bf2f(unsigned short h) {
    return __uint_as_float(((unsigned int)h) << 16);
}

// Hard-won rules (23 rounds of counters):
// 1. NO __launch_bounds__ min-wave hints on GEMM kernels (spill cliff).
// 2. Reduce register demand STRUCTURALLY — phase-split through LDS.
// 3. NEVER put __threadfence / completion counters on the hot grid (R14).
// 4. R18/R19 FAILED: wave-spread mbar, LDS weight staging — vector GEMM is
//    in-phase-L2-latency bound; tiling/staging knobs don't move it.
// 5. R20 WIN: mbar extracted to own 768-block kernel (bwd 56->45.7).
// 6. R22/R23 WIN: MFMA split-bf16 (AhBh+AhBl+AlBh, err ~2^-17) for both
//    128-K GEMMs; bwd <39, fwd improved; absmax identical to fp32 baseline.
//    B-operand layouts: bwd w2b[c'][k]=W2 native; fwd w2f[c][k]=W2[k][c].
// 7. R24: the remaining dense phases (fwd phase A, bwd gef) are the same
//    [32x32]@[32x128] shape = ONE 16x16x32 K-step. MFMA-ize both (12/24
//    MFMA per wave vs 1024/2048 VALU FMA per thread). rbf/crbf staged as
//    bf16 hi/lo; W1 pre-split in prep to [c][k]. relu/gate decided on
//    split-accurate u (flips need |u|~1e-5: rare, bounded).

// ---------------------------------------------------------------- prep
__global__ __launch_bounds__(256) void prep_kernel(
    const float* __restrict__ q, const int* __restrict__ z,
    const float* __restrict__ embed, const float* __restrict__ W1,
    const float* __restrict__ W2, const float* __restrict__ W3,
    float* __restrict__ h, float* __restrict__ W3T,
    unsigned short* __restrict__ w1fh, unsigned short* __restrict__ w1fl,
    unsigned short* __restrict__ w2fh, unsigned short* __restrict__ w2fl,
    unsigned short* __restrict__ w2bh, unsigned short* __restrict__ w2bl,
    int* __restrict__ pair_i, int* __restrict__ pair_j,
    float* __restrict__ pair_d, float* __restrict__ pair_dx,
    float* __restrict__ pair_dy, float* __restrict__ pair_dz,
    int* __restrict__ npairs_ctr,
    float* __restrict__ m, float* __restrict__ f_acc)
{
    __shared__ int   nj[MAXN];
    __shared__ float nd[MAXN], ndx[MAXN], ndy[MAXN], ndz[MAXN];
    __shared__ int cnt_s, base_s;
    int i = blockIdx.x, t = threadIdx.x;
    if (t == 0) cnt_s = 0;
    __syncthreads();
    float qx = q[i*3], qy = q[i*3+1], qz = q[i*3+2];
    for (int j = t; j < N_ATOMS; j += 256) {
        if (j == i) continue;
        float dx = qx - q[j*3], dy = qy - q[j*3+1], dz = qz - q[j*3+2];
        float d2 = dx*dx + dy*dy + dz*dz;
        if (d2 < CUT2) {
            int p = atomicAdd(&cnt_s, 1);
            if (p < MAXN) { nj[p] = j; nd[p] = sqrtf(d2);
                            ndx[p] = dx; ndy[p] = dy; ndz[p] = dz; }
        }
    }
    int g = i * 256 + t;                         // 196608 global ids
    if (g < N_ATOMS * FD) { h[g] = embed[z[g >> 7] * FD + (g & 127)]; m[g] = 0.f; }
    int g2 = g - N_ATOMS * FD;
    if (g2 >= 0 && g2 < FD * FD) {
        int r = g2 >> 7, c = g2 & 127;
        float w = W2[g2];                        // W2[r][c]
        unsigned short hb = f2bf(w);
        unsigned short lb = f2bf(w - bf2f(hb));
        w2bh[g2] = hb;                           // bwd B: w2b[c'][k]=W2[c'][k]
        w2bl[g2] = lb;                           //   (native layout)
        w2fh[c * FD + r] = hb;                   // fwd B: w2f[c][k]=W2[k][c]
        w2fl[c * FD + r] = lb;                   //   (transposed layout)
        W3T[c * FD + r] = W3[g2];
        if (g2 < NRBF * FD) {                    // W1: NRBF x FD, r=k, c=col
            float w1v = W1[g2];
            unsigned short h1 = f2bf(w1v);
            w1fh[c * NRBF + r] = h1;             // [c][k], k contiguous
            w1fl[c * NRBF + r] = f2bf(w1v - bf2f(h1));
        }
    }
    if (g < 3 * N_ATOMS) f_acc[g] = 0.f;
    __syncthreads();
    if (t == 0) base_s = atomicAdd(npairs_ctr, min(cnt_s, MAXN));
    __syncthreads();
    int cnt = min(cnt_s, MAXN), base = base_s;
    if (t < cnt) {
        pair_i[base+t] = i;      pair_j[base+t] = nj[t];
        pair_d[base+t] = nd[t];  pair_dx[base+t] = ndx[t];
        pair_dy[base+t] = ndy[t]; pair_dz[base+t] = ndz[t];
    }
}

// ---------------------------------------------------------------- fwd (PPF=32, MFMA)
// R24: phase A MFMA (u=b1+rbf@W1 split; relu+split in regs) -> phase B MFMA
// (filt=a1@W2 split) -> phase C (fp32, unchanged).
__global__ __launch_bounds__(256) void fwd_kernel(
    const unsigned short* __restrict__ w1fh, const unsigned short* __restrict__ w1fl,
    const float* __restrict__ b1,
    const unsigned short* __restrict__ w2fh, const unsigned short* __restrict__ w2fl,
    const float* __restrict__ b2, const float* __restrict__ h,
    const int* __restrict__ pair_i, const int* __restrict__ pair_j,
    const float* __restrict__ pair_d, const int* __restrict__ npairs_ctr,
    float* __restrict__ m)
{
    __shared__ __align__(16) unsigned short rbf_h[PPF * RSTU];  // 2560 B
    __shared__ __align__(16) unsigned short rbf_l[PPF * RSTU];  // 2560 B
    __shared__ __align__(16) unsigned short a1h[PPF * TST];     // 8704 B
    __shared__ __align__(16) unsigned short a1l[PPF * TST];     // 8704 B
    __shared__ float filt_s[PPF * AST];                         // 16896 B
    __shared__ int   pis[PPF], pjs[PPF];                        // 256 B (~39.7 KB)
    int t = threadIdx.x;
    int base = blockIdx.x * PPF;
    int np = npairs_ctr[0];
    if (base >= np) return;

    if (t < PPF) {
        int p = base + t; bool ok = p < np;
        pis[t] = ok ? pair_i[p] : 0;
        pjs[t] = ok ? pair_j[p] : 0;
    }
    for (int idx = t; idx < PPF * NRBF; idx += 256) {
        int p = idx >> 5, k = idx & 31;
        int gp = base + p;
        float d = (gp < np) ? pair_d[gp] : 1.0f;
        float u = d - CSTEP * (float)k;
        float r = __expf(-GAMMA_ * u * u);
        unsigned short hb = f2bf(r);
        rbf_h[p * RSTU + k] = hb;
        rbf_l[p * RSTU + k] = f2bf(r - bf2f(hb));
    }
    __syncthreads();

    // Phase A (MFMA): u = b1 + rbf@W1 (split, 12 MFMA); relu+split in regs.
    {
        int wid = t >> 6, lane = t & 63;
        int lr = lane & 15, lg = lane >> 4;
        int c0 = (2 * wid + 0) * 16 + lr;
        int c1 = (2 * wid + 1) * 16 + lr;
        float bb0 = b1[c0], bb1 = b1[c1];
        f32x4 u00 = {bb0,bb0,bb0,bb0}, u01 = {bb1,bb1,bb1,bb1};
        f32x4 u10 = {bb0,bb0,bb0,bb0}, u11 = {bb1,bb1,bb1,bb1};
        short8v rh0 = *(const short8v*)(rbf_h + lr * RSTU + lg * 8);
        short8v rh1 = *(const short8v*)(rbf_h + (16+lr) * RSTU + lg * 8);
        short8v rl0 = *(const short8v*)(rbf_l + lr * RSTU + lg * 8);
        short8v rl1 = *(const short8v*)(rbf_l + (16+lr) * RSTU + lg * 8);
        short8v bh0 = *(const short8v*)(w1fh + c0 * NRBF + lg * 8);
        short8v bh1 = *(const short8v*)(w1fh + c1 * NRBF + lg * 8);
        short8v bl0 = *(const short8v*)(w1fl + c0 * NRBF + lg * 8);
        short8v bl1 = *(const short8v*)(w1fl + c1 * NRBF + lg * 8);
        u00 = MFMA_B16(rh0, bh0, u00, 0,0,0); u01 = MFMA_B16(rh0, bh1, u01, 0,0,0);
        u10 = MFMA_B16(rh1, bh0, u10, 0,0,0); u11 = MFMA_B16(rh1, bh1, u11, 0,0,0);
        u00 = MFMA_B16(rh0, bl0, u00, 0,0,0); u01 = MFMA_B16(rh0, bl1, u01, 0,0,0);
        u10 = MFMA_B16(rh1, bl0, u10, 0,0,0); u11 = MFMA_B16(rh1, bl1, u11, 0,0,0);
        u00 = MFMA_B16(rl0, bh0, u00, 0,0,0); u01 = MFMA_B16(rl0, bh1, u01, 0,0,0);
        u10 = MFMA_B16(rl1, bh0, u10, 0,0,0); u11 = MFMA_B16(rl1, bh1, u11, 0,0,0);
        // C/D: col=lane&15, row=(lane>>4)*4+reg  [verified]
#pragma unroll
        for (int r = 0; r < 4; r++) {
            int pA = lg * 4 + r, pB = 16 + lg * 4 + r;
            float v; unsigned short hb;
            v = fmaxf(u00[r], 0.f); hb = f2bf(v);
            a1h[pA * TST + c0] = hb; a1l[pA * TST + c0] = f2bf(v - bf2f(hb));
            v = fmaxf(u01[r], 0.f); hb = f2bf(v);
            a1h[pA * TST + c1] = hb; a1l[pA * TST + c1] = f2bf(v - bf2f(hb));
            v = fmaxf(u10[r], 0.f); hb = f2bf(v);
            a1h[pB * TST + c0] = hb; a1l[pB * TST + c0] = f2bf(v - bf2f(hb));
            v = fmaxf(u11[r], 0.f); hb = f2bf(v);
            a1h[pB * TST + c1] = hb; a1l[pB * TST + c1] = f2bf(v - bf2f(hb));
        }
    }
    __syncthreads();

    // Phase B: filt = a1 @ W2 via MFMA (4 ksteps, split AhBh+AhBl+AlBh).
    {
        int wid = t >> 6, lane = t & 63;
        int lr = lane & 15, lg = lane >> 4;
        int c0 = (2 * wid + 0) * 16 + lr;
        int c1 = (2 * wid + 1) * 16 + lr;
        f32x4 acc00 = {0.f,0.f,0.f,0.f}, acc01 = {0.f,0.f,0.f,0.f};
        f32x4 acc10 = {0.f,0.f,0.f,0.f}, acc11 = {0.f,0.f,0.f,0.f};
#pragma unroll
        for (int ks = 0; ks < 4; ks++) {
            int kb = ks * 32 + lg * 8;
            short8v ah0 = *(const short8v*)(a1h + (lr     ) * TST + kb);
            short8v ah1 = *(const short8v*)(a1h + (16 + lr) * TST + kb);
            short8v al0 = *(const short8v*)(a1l + (lr     ) * TST + kb);
            short8v al1 = *(const short8v*)(a1l + (16 + lr) * TST + kb);
            short8v bh0 = *(const short8v*)(w2fh + c0 * FD + kb);
            short8v bh1 = *(const short8v*)(w2fh + c1 * FD + kb);
            short8v bl0 = *(const short8v*)(w2fl + c0 * FD + kb);
            short8v bl1 = *(const short8v*)(w2fl + c1 * FD + kb);
            acc00 = MFMA_B16(ah0, bh0, acc00, 0,0,0);
            acc01 = MFMA_B16(ah0, bh1, acc01, 0,0,0);
            acc10 = MFMA_B16(ah1, bh0, acc10, 0,0,0);
            acc11 = MFMA_B16(ah1, bh1, acc11, 0,0,0);
            acc00 = MFMA_B16(ah0, bl0, acc00, 0,0,0);
            acc01 = MFMA_B16(ah0, bl1, acc01, 0,0,0);
            acc10 = MFMA_B16(ah1, bl0, acc10, 0,0,0);
            acc11 = MFMA_B16(ah1, bl1, acc11, 0,0,0);
            acc00 = MFMA_B16(al0, bh0, acc00, 0,0,0);
            acc01 = MFMA_B16(al0, bh1, acc01, 0,0,0);
            acc10 = MFMA_B16(al1, bh0, acc10, 0,0,0);
            acc11 = MFMA_B16(al1, bh1, acc11, 0,0,0);
        }
#pragma unroll
        for (int r = 0; r < 4; r++) {
            int pA = lg * 4 + r, pB = 16 + lg * 4 + r;
            filt_s[pA * AST + c0] = acc00[r];
            filt_s[pA * AST + c1] = acc01[r];
            filt_s[pB * AST + c0] = acc10[r];
            filt_s[pB * AST + c1] = acc11[r];
        }
    }
    __syncthreads();

    // Phase C: m[i,c] += (filt[p][c]+b2[c]) * h[j_p][c]; thread = (c, half)
    {
        int c = t & 127, ph = t >> 7;
        float b2c = b2[c];
        float r = 0.f;
        int p0 = ph * 16;
        int cur_i = pis[p0];
        for (int p = p0; p < p0 + 16; p++) {
            int ip = pis[p];
            if (ip != cur_i) {
                atomicAdd(m + cur_i * FD + c, r);
                r = 0.f; cur_i = ip;
            }
            if (base + p < np)
                r += (filt_s[p * AST + c] + b2c) * h[pjs[p] * FD + c];
        }
        atomicAdd(m + cur_i * FD + c, r);
    }
}

// ---------------------------------------------------------------- mbar (R20)
__global__ __launch_bounds__(256) void mbar_kernel(
    const float* __restrict__ m, const float* __restrict__ W3,
    const float* __restrict__ W3T, const float* __restrict__ wout,
    float* __restrict__ mbar)
{
    __shared__ float mrow[FD];
    __shared__ float gb[FD];
    __shared__ float part[256];
    int i = blockIdx.x, t = threadIdx.x;
    if (t < FD) mrow[t] = m[i * FD + t];
    __syncthreads();
    int c = t & 127, hh = t >> 7;          // hh = 0/1 -> f half
    int f0 = hh * 64;
    float g = 0.f;
#pragma unroll 8
    for (int f = f0; f < f0 + 64; f++) g += mrow[f] * W3[f * FD + c];
    part[t] = g;
    __syncthreads();
    if (t < FD) gb[t] = (part[t] + part[t + 128] > 0.f) ? wout[t] : 0.f;
    __syncthreads();
    float mb = 0.f;
#pragma unroll 8
    for (int f = f0; f < f0 + 64; f++) mb += gb[f] * W3T[f * FD + c];
    part[t] = mb;
    __syncthreads();
    if (t < FD) mbar[i * FD + t] = part[t] + part[t + 128];
}

// ---------------------------------------------------------------- bwd (PPBW=32, MFMA)
// R24: stage(bf16 rbf/crbf) -> {ts-fill + gef MFMA (u1/ef, gate in regs)} ->
// GEMM MFMA -> gef-fold + shuffle reduce -> scatter. 2 barriers.
__global__ __launch_bounds__(256) void bwd_kernel(
    const unsigned short* __restrict__ w1fh, const unsigned short* __restrict__ w1fl,
    const float* __restrict__ b1,
    const unsigned short* __restrict__ w2bh, const unsigned short* __restrict__ w2bl,
    const float* __restrict__ h, const float* __restrict__ mbar,
    const int* __restrict__ pair_i, const int* __restrict__ pair_j,
    const float* __restrict__ pair_d, const float* __restrict__ pair_dx,
    const float* __restrict__ pair_dy, const float* __restrict__ pair_dz,
    const int* __restrict__ npairs_ctr, float* __restrict__ f_acc)
{
    __shared__ __align__(16) unsigned short rbf_h[PPBW * RSTU];   // 2560 B
    __shared__ __align__(16) unsigned short rbf_l[PPBW * RSTU];   // 2560 B
    __shared__ __align__(16) unsigned short crbf_h[PPBW * RSTU];  // 2560 B
    __shared__ __align__(16) unsigned short crbf_l[PPBW * RSTU];  // 2560 B
    __shared__ float gef[PPBW * AST];                             // 16896 B
    __shared__ __align__(16) unsigned short ts_h[PPBW * TST];     // 8704 B
    __shared__ __align__(16) unsigned short ts_l[PPBW * TST];     // 8704 B
    __shared__ float sred[4 * PPBW];                              // 512 B
    __shared__ int   pis[PPBW], pjs[PPBW];                        // 256 B (~45.3 KB)
    int t = threadIdx.x;
    int base = blockIdx.x * PPBW;
    int np = npairs_ctr[0];
    if (base >= np) return;

    if (t < PPBW) {
        int p = base + t; bool ok = p < np;
        pis[t] = ok ? pair_i[p] : 0;
        pjs[t] = ok ? pair_j[p] : 0;
    }
    for (int idx = t; idx < PPBW * NRBF; idx += 256) {
        int p = idx >> 5, k = idx & 31;
        int gp = base + p;
        float d = (gp < np) ? pair_d[gp] : 1.0f;
        float u = d - CSTEP * (float)k;
        float r = __expf(-GAMMA_ * u * u);
        float cd = -2.f * GAMMA_ * u * r;
        unsigned short hb = f2bf(r);
        rbf_h[p * RSTU + k] = hb;
        rbf_l[p * RSTU + k] = f2bf(r - bf2f(hb));
        unsigned short hc = f2bf(cd);
        crbf_h[p * RSTU + k] = hc;
        crbf_l[p * RSTU + k] = f2bf(cd - bf2f(hc));
    }
    __syncthreads();                       // pis/pjs + rbf/crbf ready

    // ts-fill: ts[p][c] = mbar[i_p][c] * h[j_p][c] -> bf16 hi/lo in LDS
    for (int idx = t; idx < PPBW * 32; idx += 256) {
        int p = idx >> 5, c4g = (idx & 31) * 4;
        float4 mb4 = *(const float4*)(mbar + pis[p] * FD + c4g);
        float4 hj4 = *(const float4*)(h    + pjs[p] * FD + c4g);
        float v0 = mb4.x*hj4.x, v1 = mb4.y*hj4.y, v2 = mb4.z*hj4.z, v3 = mb4.w*hj4.w;
        ushort4 hv, lv;
        hv.x = f2bf(v0); lv.x = f2bf(v0 - bf2f(hv.x));
        hv.y = f2bf(v1); lv.y = f2bf(v1 - bf2f(hv.y));
        hv.z = f2bf(v2); lv.z = f2bf(v2 - bf2f(hv.z));
        hv.w = f2bf(v3); lv.w = f2bf(v3 - bf2f(hv.w));
        *(ushort4*)(ts_h + p * TST + c4g) = hv;
        *(ushort4*)(ts_l + p * TST + c4g) = lv;
    }

    // gef phase (MFMA): u1 = b1 + rbf@W1, ef = crbf@W1 (split); gate in regs.
    {
        int wid = t >> 6, lane = t & 63;
        int lr = lane & 15, lg = lane >> 4;
        int c0 = (2 * wid + 0) * 16 + lr;
        int c1 = (2 * wid + 1) * 16 + lr;
        float bb0 = b1[c0], bb1 = b1[c1];
        f32x4 u00 = {bb0,bb0,bb0,bb0}, u01 = {bb1,bb1,bb1,bb1};
        f32x4 u10 = {bb0,bb0,bb0,bb0}, u11 = {bb1,bb1,bb1,bb1};
        f32x4 e00 = {0.f,0.f,0.f,0.f}, e01 = {0.f,0.f,0.f,0.f};
        f32x4 e10 = {0.f,0.f,0.f,0.f}, e11 = {0.f,0.f,0.f,0.f};
        short8v rh0 = *(const short8v*)(rbf_h + lr * RSTU + lg * 8);
        short8v rh1 = *(const short8v*)(rbf_h + (16+lr) * RSTU + lg * 8);
        short8v rl0 = *(const short8v*)(rbf_l + lr * RSTU + lg * 8);
        short8v rl1 = *(const short8v*)(rbf_l + (16+lr) * RSTU + lg * 8);
        short8v ch0 = *(const short8v*)(crbf_h + lr * RSTU + lg * 8);
        short8v ch1 = *(const short8v*)(crbf_h + (16+lr) * RSTU + lg * 8);
        short8v cl0 = *(const short8v*)(crbf_l + lr * RSTU + lg * 8);
        short8v cl1 = *(const short8v*)(crbf_l + (16+lr) * RSTU + lg * 8);
        short8v bh0 = *(const short8v*)(w1fh + c0 * NRBF + lg * 8);
        short8v bh1 = *(const short8v*)(w1fh + c1 * NRBF + lg * 8);
        short8v bl0 = *(const short8v*)(w1fl + c0 * NRBF + lg * 8);
        short8v bl1 = *(const short8v*)(w1fl + c1 * NRBF + lg * 8);
        u00 = MFMA_B16(rh0, bh0, u00, 0,0,0); u01 = MFMA_B16(rh0, bh1, u01, 0,0,0);
        u10 = MFMA_B16(rh1, bh0, u10, 0,0,0); u11 = MFMA_B16(rh1, bh1, u11, 0,0,0);
        u00 = MFMA_B16(rh0, bl0, u00, 0,0,0); u01 = MFMA_B16(rh0, bl1, u01, 0,0,0);
        u10 = MFMA_B16(rh1, bl0, u10, 0,0,0); u11 = MFMA_B16(rh1, bl1, u11, 0,0,0);
        u00 = MFMA_B16(rl0, bh0, u00, 0,0,0); u01 = MFMA_B16(rl0, bh1, u01, 0,0,0);
        u10 = MFMA_B16(rl1, bh0, u10, 0,0,0); u11 = MFMA_B16(rl1, bh1, u11, 0,0,0);
        e00 = MFMA_B16(ch0, bh0, e00, 0,0,0); e01 = MFMA_B16(ch0, bh1, e01, 0,0,0);
        e10 = MFMA_B16(ch1, bh0, e10, 0,0,0); e11 = MFMA_B16(ch1, bh1, e11, 0,0,0);
        e00 = MFMA_B16(ch0, bl0, e00, 0,0,0); e01 = MFMA_B16(ch0, bl1, e01, 0,0,0);
        e10 = MFMA_B16(ch1, bl0, e10, 0,0,0); e11 = MFMA_B16(ch1, bl1, e11, 0,0,0);
        e00 = MFMA_B16(cl0, bh0, e00, 0,0,0); e01 = MFMA_B16(cl0, bh1, e01, 0,0,0);
        e10 = MFMA_B16(cl1, bh0, e10, 0,0,0); e11 = MFMA_B16(cl1, bh1, e11, 0,0,0);
#pragma unroll
        for (int r = 0; r < 4; r++) {
            int pA = lg * 4 + r, pB = 16 + lg * 4 + r;
            gef[pA * AST + c0] = (u00[r] > 0.f) ? e00[r] : 0.f;
            gef[pA * AST + c1] = (u01[r] > 0.f) ? e01[r] : 0.f;
            gef[pB * AST + c0] = (u10[r] > 0.f) ? e10[r] : 0.f;
            gef[pB * AST + c1] = (u11[r] > 0.f) ? e11[r] : 0.f;
        }
    }
    __syncthreads();                       // ts_h/ts_l + gef ready

    // MFMA GEMM: du1 = ts @ W2T  (B[k][c']=W2[c'][k] from native-layout w2b).
    {
        int wid = t >> 6, lane = t & 63;
        int lr = lane & 15, lg = lane >> 4;
        int c0 = (2 * wid + 0) * 16 + lr;
        int c1 = (2 * wid + 1) * 16 + lr;
        f32x4 acc00 = {0.f,0.f,0.f,0.f}, acc01 = {0.f,0.f,0.f,0.f};
        f32x4 acc10 = {0.f,0.f,0.f,0.f}, acc11 = {0.f,0.f,0.f,0.f};
#pragma unroll
        for (int ks = 0; ks < 4; ks++) {
            int kb = ks * 32 + lg * 8;
            short8v ah0 = *(const short8v*)(ts_h + (lr     ) * TST + kb);
            short8v ah1 = *(const short8v*)(ts_h + (16 + lr) * TST + kb);
            short8v al0 = *(const short8v*)(ts_l + (lr     ) * TST + kb);
            short8v al1 = *(const short8v*)(ts_l + (16 + lr) * TST + kb);
            short8v bh0 = *(const short8v*)(w2bh + c0 * FD + kb);
            short8v bh1 = *(const short8v*)(w2bh + c1 * FD + kb);
            short8v bl0 = *(const short8v*)(w2bl + c0 * FD + kb);
            short8v bl1 = *(const short8v*)(w2bl + c1 * FD + kb);
            acc00 = MFMA_B16(ah0, bh0, acc00, 0,0,0);
            acc01 = MFMA_B16(ah0, bh1, acc01, 0,0,0);
            acc10 = MFMA_B16(ah1, bh0, acc10, 0,0,0);
            acc11 = MFMA_B16(ah1, bh1, acc11, 0,0,0);
            acc00 = MFMA_B16(ah0, bl0, acc00, 0,0,0);
            acc01 = MFMA_B16(ah0, bl1, acc01, 0,0,0);
            acc10 = MFMA_B16(ah1, bl0, acc10, 0,0,0);
            acc11 = MFMA_B16(ah1, bl1, acc11, 0,0,0);
            acc00 = MFMA_B16(al0, bh0, acc00, 0,0,0);
            acc01 = MFMA_B16(al0, bh1, acc01, 0,0,0);
            acc10 = MFMA_B16(al1, bh0, acc10, 0,0,0);
            acc11 = MFMA_B16(al1, bh1, acc11, 0,0,0);
        }
        // Epilogue: fold gef, reduce over cols. C/D: col=lane&15,
        // row=(lane>>4)*4+reg  [verified layout].
        float part[8];
#pragma unroll
        for (int r = 0; r < 4; r++) {
            int pA = lg * 4 + r;           // mtile 0
            int pB = 16 + lg * 4 + r;      // mtile 1
            part[r]     = acc00[r] * gef[pA * AST + c0] + acc01[r] * gef[pA * AST + c1];
            part[4 + r] = acc10[r] * gef[pB * AST + c0] + acc11[r] * gef[pB * AST + c1];
        }
#pragma unroll
        for (int mask = 1; mask < 16; mask <<= 1) {
#pragma unroll
            for (int e = 0; e < 8; e++) part[e] += __shfl_xor(part[e], mask, 64);
        }
        if (lr == 0) {
#pragma unroll
            for (int r = 0; r < 4; r++) {
                sred[wid * PPBW + lg * 4 + r]      = part[r];
                sred[wid * PPBW + 16 + lg * 4 + r] = part[4 + r];
            }
        }
    }
    __syncthreads();

    // Final per-pair scatter (32 pairs by threads 0..31)
    if (t < PPBW) {
        int gp = base + t;
        if (gp < np) {
            float s = sred[t] + sred[PPBW + t] + sred[2*PPBW + t] + sred[3*PPBW + t];
            int ii = pis[t], jj = pjs[t];
            float coef = s / pair_d[gp];
            float fx = coef * pair_dx[gp];
            float fy = coef * pair_dy[gp];
            float fz = coef * pair_dz[gp];
            atomicAdd(f_acc + ii*3 + 0, -fx);
            atomicAdd(f_acc + ii*3 + 1, -fy);
            atomicAdd(f_acc + ii*3 + 2, -fz);
            atomicAdd(f_acc + jj*3 + 0, fx);
            atomicAdd(f_acc + jj*3 + 1, fy);
            atomicAdd(f_acc + jj*3 + 2, fz);
        }
    }
}

// ---------------------------------------------------------------- finalize
__global__ __launch_bounds__(256) void fin_kernel(
    const float* __restrict__ v, const float* __restrict__ mass,
    const float* __restrict__ p_eta, const float* __restrict__ f_acc,
    float* __restrict__ out)
{
    __shared__ float red[256];
    int t = threadIdx.x;
    float ke = 0.f;
    float c = p_eta[0] / Q0_F;
    for (int idx = t; idx < 3 * N_ATOMS; idx += 256) {
        int a = idx / 3;
        float vv = v[idx], mi = mass[a];
        out[DVDT_OFF + idx] = (f_acc[idx] - c * vv * mi) / mi;
        out[V_OFF + idx] = vv;
        ke += 0.5f * mi * vv * vv;
    }
    red[t] = ke;
    __syncthreads();
    for (int s = 128; s > 0; s >>= 1) {
        if (t < s) red[t] += red[t + s];
        __syncthreads();
    }
    if (t == 0) {
        float k0 = red[0];
        float e0 = p_eta[0], e1 = p_eta[1], e2 = p_eta[2], e3 = p_eta[3];
        out[PETA_OFF + 0] = 2.f * (k0 - TARGET_KE) - e0 * e1 / QI_F;
        out[PETA_OFF + 1] = e0 * e0 / Q0_F - KT_F - e1 * e2 / QI_F;
        out[PETA_OFF + 2] = e1 * e1 / QI_F - KT_F - e2 * e3 / QI_F;
        out[PETA_OFF + 3] = e2 * e2 / QI_F - KT_F;
    }
}

// ---------------------------------------------------------------- launch
extern "C" void kernel_launch(void* const* d_in, const int* in_sizes, int n_in,
                              void* d_out, int out_size, void* d_ws, size_t ws_size,
                              hipStream_t stream)
{
    const float* v     = (const float*)d_in[0];
    const float* q     = (const float*)d_in[1];
    const float* p_eta = (const float*)d_in[2];
    const float* mass  = (const float*)d_in[3];
    const float* embed = (const float*)d_in[4];
    const float* W1    = (const float*)d_in[5];
    const float* b1    = (const float*)d_in[6];
    const float* W2    = (const float*)d_in[7];
    const float* b2    = (const float*)d_in[8];
    const float* W3    = (const float*)d_in[9];
    const float* wout  = (const float*)d_in[10];
    const int*   z     = (const int*)d_in[11];
    float* out = (float*)d_out;

    float* h     = (float*)d_ws;
    float* W2T_unused = h + N_ATOMS * FD;        // slot kept (layout stability)
    float* W3T   = W2T_unused + FD * FD;
    float* m     = W3T + FD * FD;
    float* f_acc = m + N_ATOMS * FD;
    float* pair_d  = f_acc + 3 * N_ATOMS;
    float* pair_dx = pair_d + N_ATOMS * MAXN;
    float* pair_dy = pair_dx + N_ATOMS * MAXN;
    float* pair_dz = pair_dy + N_ATOMS * MAXN;
    int* pair_i = (int*)(pair_dz + N_ATOMS * MAXN);
    int* pair_j = pair_i + N_ATOMS * MAXN;
    int* npairs_ctr = pair_j + N_ATOMS * MAXN;
    float* mbar  = (float*)(npairs_ctr + 64);     // 64-int pad for alignment
    unsigned short* w2bh = (unsigned short*)(mbar + N_ATOMS * FD);
    unsigned short* w2bl = w2bh + FD * FD;
    unsigned short* w2fh = w2bl + FD * FD;
    unsigned short* w2fl = w2fh + FD * FD;
    unsigned short* w1fh = w2fl + FD * FD;
    unsigned short* w1fl = w1fh + NRBF * FD;

    hipMemsetAsync(npairs_ctr, 0, sizeof(int), stream);

    prep_kernel<<<N_ATOMS, 256, 0, stream>>>(q, z, embed, W1, W2, W3, h, W3T,
                                             w1fh, w1fl, w2fh, w2fl, w2bh, w2bl,
                                             pair_i, pair_j, pair_d,
                                             pair_dx, pair_dy, pair_dz,
                                             npairs_ctr, m, f_acc);
    fwd_kernel<<<FTILES, 256, 0, stream>>>(w1fh, w1fl, b1, w2fh, w2fl, b2, h,
                                           pair_i, pair_j, pair_d, npairs_ctr, m);
    mbar_kernel<<<N_ATOMS, 256, 0, stream>>>(m, W3, W3T, wout, mbar);
    bwd_kernel<<<BTILES, 256, 0, stream>>>(w1fh, w1fl, b1, w2bh, w2bl, h, mbar,
                                           pair_i, pair_j, pair_d, pair_dx,
                                           pair_dy, pair_dz, npairs_ctr, f_acc);
    fin_kernel<<<1, 256, 0, stream>>>(v, mass, p_eta, f_acc, out);
}

// Round 8
// 142.870 us; speedup vs baseline: 1.2522x; 1.0089x over previous
//
#include <hip/hip_runtime.h>
#include <math.h>

// Problem constants (match reference)
#define N_ATOMS 768
#define FD 128          // feature width
#define NRBF 32
#define MAXN 64         // per-atom neighbor cap (mean ~26)
#define PPF 32          // fwd: pairs per block (2 M-tiles of 16)
#define PPBW 32         // bwd: pairs per block (2 M-tiles of 16) — MUST equal PPF (gate mask reuse)
#define FTILES (N_ATOMS * MAXN / PPF)     // 1536
#define BTILES (N_ATOMS * MAXN / PPBW)    // 1536
#define AST 132         // padded LDS stride for [*][128] f32 tiles
#define TST 136         // padded LDS stride for [*][128] bf16 (ushort) tiles
#define RSTU 40         // padded ushort stride for [*][32] bf16 rbf tiles (80B, 16B-aligned)

constexpr float  CUT2   = 25.0f;
constexpr float  GAMMA_ = 40.96f;            // 1/(5/32)^2
constexpr float  CSTEP  = 5.0f / 31.0f;      // linspace(0,5,32) step
constexpr double KB_D   = 8.617330337217213e-05;
constexpr double KT_D   = 300.0 * KB_D;
constexpr float  KT_F   = (float)KT_D;
constexpr float  TARGET_KE = (float)(0.5 * 2304.0 * KT_D);
constexpr float  Q0_F   = (float)(2.0 * 2304.0 * KT_D * 400.0);  // Q[0]
constexpr float  QI_F   = (float)(2.0 * KT_D * 400.0);           // Q[1..3]

#define DVDT_OFF 0
#define V_OFF    (3 * N_ATOMS)
#define PETA_OFF (6 * N_ATOMS)

using short8v = __attribute__((ext_vector_type(8))) short;
using f32x4   = __attribute__((ext_vector_type(4))) float;

#define MFMA_B16 __builtin_amdgcn_mfma_f32_16x16x32_bf16

__device__ __forceinline__ unsigned short f2bf(float x) {
    unsigned int u = __float_as_uint(x);
    u += 0x7FFF + ((u >> 16) & 1);           // round-to-nearest-even
    return (unsigned short)(u >> 16);
}
__device__ __forceinline__ float bf2f(unsigned short h) {
    return __uint_as_float(((unsigned int)h) << 16);
}

// Hard-won rules (24 rounds of counters):
// 1. NO __launch_bounds__ min-wave hints on GEMM kernels (spill cliff).
// 2. Reduce register demand STRUCTURALLY — phase-split through LDS.
// 3. NEVER put __threadfence / completion counters on the hot grid (R14).
// 4. R18/R19 FAILED: wave-spread mbar, LDS weight staging — vector GEMM was
//    in-phase-L2-latency bound; tiling/staging knobs don't move it.
// 5. R20 WIN: mbar extracted to own 768-block kernel (bwd 56->45.7).
// 6. R22-R24 WIN: MFMA split-bf16 (AhBh+AhBl+AlBh, err ~2^-17) for ALL dense
//    phases; absmax identical to fp32 baseline. Layouts: bwd w2b native,
//    fwd w2f[c][k]=W2[k][c], w1f[c][k]=W1[k][c]. C/D: col=lane&15,
//    row=(lane>>4)*4+reg (verified by exact absmax match).
// 7. R25: (a) bwd gef recomputed fwd's u1 just for the relu gate — fwd now
//    stores 16-bit gate mask per thread (same tile/lane mapping, PPF==PPBW),
//    bwd gef: 24->12 MFMA, rbf staging dropped. (b) gef produced and consumed
//    at the SAME thread/reg position -> keep in registers (kills 16.9 KB LDS
//    + a barrier). (c) fwd phase-C h-rows prefetched into regs before phase A
//    (overlap A+B). (d) mbar GEMVs read transposed-operand rows (contiguous
//    float4 per lane).

// ---------------------------------------------------------------- prep
__global__ __launch_bounds__(256) void prep_kernel(
    const float* __restrict__ q, const int* __restrict__ z,
    const float* __restrict__ embed, const float* __restrict__ W1,
    const float* __restrict__ W2, const float* __restrict__ W3,
    float* __restrict__ h, float* __restrict__ W3T,
    unsigned short* __restrict__ w1fh, unsigned short* __restrict__ w1fl,
    unsigned short* __restrict__ w2fh, unsigned short* __restrict__ w2fl,
    unsigned short* __restrict__ w2bh, unsigned short* __restrict__ w2bl,
    int* __restrict__ pair_i, int* __restrict__ pair_j,
    float* __restrict__ pair_d, float* __restrict__ pair_dx,
    float* __restrict__ pair_dy, float* __restrict__ pair_dz,
    int* __restrict__ npairs_ctr,
    float* __restrict__ m, float* __restrict__ f_acc)
{
    __shared__ int   nj[MAXN];
    __shared__ float nd[MAXN], ndx[MAXN], ndy[MAXN], ndz[MAXN];
    __shared__ int cnt_s, base_s;
    int i = blockIdx.x, t = threadIdx.x;
    if (t == 0) cnt_s = 0;
    __syncthreads();
    float qx = q[i*3], qy = q[i*3+1], qz = q[i*3+2];
    for (int j = t; j < N_ATOMS; j += 256) {
        if (j == i) continue;
        float dx = qx - q[j*3], dy = qy - q[j*3+1], dz = qz - q[j*3+2];
        float d2 = dx*dx + dy*dy + dz*dz;
        if (d2 < CUT2) {
            int p = atomicAdd(&cnt_s, 1);
            if (p < MAXN) { nj[p] = j; nd[p] = sqrtf(d2);
                            ndx[p] = dx; ndy[p] = dy; ndz[p] = dz; }
        }
    }
    int g = i * 256 + t;                         // 196608 global ids
    if (g < N_ATOMS * FD) { h[g] = embed[z[g >> 7] * FD + (g & 127)]; m[g] = 0.f; }
    int g2 = g - N_ATOMS * FD;
    if (g2 >= 0 && g2 < FD * FD) {
        int r = g2 >> 7, c = g2 & 127;
        float w = W2[g2];                        // W2[r][c]
        unsigned short hb = f2bf(w);
        unsigned short lb = f2bf(w - bf2f(hb));
        w2bh[g2] = hb;                           // bwd B: w2b[c'][k]=W2[c'][k]
        w2bl[g2] = lb;                           //   (native layout)
        w2fh[c * FD + r] = hb;                   // fwd B: w2f[c][k]=W2[k][c]
        w2fl[c * FD + r] = lb;                   //   (transposed layout)
        W3T[c * FD + r] = W3[g2];
        if (g2 < NRBF * FD) {                    // W1: NRBF x FD, r=k, c=col
            float w1v = W1[g2];
            unsigned short h1 = f2bf(w1v);
            w1fh[c * NRBF + r] = h1;             // [c][k], k contiguous
            w1fl[c * NRBF + r] = f2bf(w1v - bf2f(h1));
        }
    }
    if (g < 3 * N_ATOMS) f_acc[g] = 0.f;
    __syncthreads();
    if (t == 0) base_s = atomicAdd(npairs_ctr, min(cnt_s, MAXN));
    __syncthreads();
    int cnt = min(cnt_s, MAXN), base = base_s;
    if (t < cnt) {
        pair_i[base+t] = i;      pair_j[base+t] = nj[t];
        pair_d[base+t] = nd[t];  pair_dx[base+t] = ndx[t];
        pair_dy[base+t] = ndy[t]; pair_dz[base+t] = ndz[t];
    }
}

// ---------------------------------------------------------------- fwd (PPF=32, MFMA)
// R25: stage -> h-prefetch -> phase A MFMA (+gate mask store) -> phase B MFMA
// -> phase C (prefetched h).
__global__ __launch_bounds__(256) void fwd_kernel(
    const unsigned short* __restrict__ w1fh, const unsigned short* __restrict__ w1fl,
    const float* __restrict__ b1,
    const unsigned short* __restrict__ w2fh, const unsigned short* __restrict__ w2fl,
    const float* __restrict__ b2, const float* __restrict__ h,
    const int* __restrict__ pair_i, const int* __restrict__ pair_j,
    const float* __restrict__ pair_d, const int* __restrict__ npairs_ctr,
    float* __restrict__ m, unsigned short* __restrict__ gatem)
{
    __shared__ __align__(16) unsigned short rbf_h[PPF * RSTU];  // 2560 B
    __shared__ __align__(16) unsigned short rbf_l[PPF * RSTU];  // 2560 B
    __shared__ __align__(16) unsigned short a1h[PPF * TST];     // 8704 B
    __shared__ __align__(16) unsigned short a1l[PPF * TST];     // 8704 B
    __shared__ float filt_s[PPF * AST];                         // 16896 B
    __shared__ int   pis[PPF], pjs[PPF];                        // 256 B (~39.7 KB)
    int t = threadIdx.x;
    int base = blockIdx.x * PPF;
    int np = npairs_ctr[0];
    if (base >= np) return;

    if (t < PPF) {
        int p = base + t; bool ok = p < np;
        pis[t] = ok ? pair_i[p] : 0;
        pjs[t] = ok ? pair_j[p] : 0;
    }
    for (int idx = t; idx < PPF * NRBF; idx += 256) {
        int p = idx >> 5, k = idx & 31;
        int gp = base + p;
        float d = (gp < np) ? pair_d[gp] : 1.0f;
        float u = d - CSTEP * (float)k;
        float r = __expf(-GAMMA_ * u * u);
        unsigned short hb = f2bf(r);
        rbf_h[p * RSTU + k] = hb;
        rbf_l[p * RSTU + k] = f2bf(r - bf2f(hb));
    }
    __syncthreads();

    // Phase-C h-row prefetch: issue the 16 scattered loads now so they
    // overlap phases A+B instead of stalling phase C.
    float hv[16];
    {
        int c = t & 127, ph = t >> 7;
        int p0 = ph * 16;
#pragma unroll
        for (int e = 0; e < 16; e++) hv[e] = h[pjs[p0 + e] * FD + c];
    }

    // Phase A (MFMA): u = b1 + rbf@W1 (split, 12 MFMA); relu+split in regs;
    // store 16-bit relu gate mask for bwd reuse.
    {
        int wid = t >> 6, lane = t & 63;
        int lr = lane & 15, lg = lane >> 4;
        int c0 = (2 * wid + 0) * 16 + lr;
        int c1 = (2 * wid + 1) * 16 + lr;
        float bb0 = b1[c0], bb1 = b1[c1];
        f32x4 u00 = {bb0,bb0,bb0,bb0}, u01 = {bb1,bb1,bb1,bb1};
        f32x4 u10 = {bb0,bb0,bb0,bb0}, u11 = {bb1,bb1,bb1,bb1};
        short8v rh0 = *(const short8v*)(rbf_h + lr * RSTU + lg * 8);
        short8v rh1 = *(const short8v*)(rbf_h + (16+lr) * RSTU + lg * 8);
        short8v rl0 = *(const short8v*)(rbf_l + lr * RSTU + lg * 8);
        short8v rl1 = *(const short8v*)(rbf_l + (16+lr) * RSTU + lg * 8);
        short8v bh0 = *(const short8v*)(w1fh + c0 * NRBF + lg * 8);
        short8v bh1 = *(const short8v*)(w1fh + c1 * NRBF + lg * 8);
        short8v bl0 = *(const short8v*)(w1fl + c0 * NRBF + lg * 8);
        short8v bl1 = *(const short8v*)(w1fl + c1 * NRBF + lg * 8);
        u00 = MFMA_B16(rh0, bh0, u00, 0,0,0); u01 = MFMA_B16(rh0, bh1, u01, 0,0,0);
        u10 = MFMA_B16(rh1, bh0, u10, 0,0,0); u11 = MFMA_B16(rh1, bh1, u11, 0,0,0);
        u00 = MFMA_B16(rh0, bl0, u00, 0,0,0); u01 = MFMA_B16(rh0, bl1, u01, 0,0,0);
        u10 = MFMA_B16(rh1, bl0, u10, 0,0,0); u11 = MFMA_B16(rh1, bl1, u11, 0,0,0);
        u00 = MFMA_B16(rl0, bh0, u00, 0,0,0); u01 = MFMA_B16(rl0, bh1, u01, 0,0,0);
        u10 = MFMA_B16(rl1, bh0, u10, 0,0,0); u11 = MFMA_B16(rl1, bh1, u11, 0,0,0);
        // C/D: col=lane&15, row=(lane>>4)*4+reg  [verified]
        unsigned int mk = 0;
#pragma unroll
        for (int r = 0; r < 4; r++) {
            int pA = lg * 4 + r, pB = 16 + lg * 4 + r;
            float v; unsigned short hb;
            if (u00[r] > 0.f) mk |= 1u << r;
            if (u01[r] > 0.f) mk |= 1u << (4 + r);
            if (u10[r] > 0.f) mk |= 1u << (8 + r);
            if (u11[r] > 0.f) mk |= 1u << (12 + r);
            v = fmaxf(u00[r], 0.f); hb = f2bf(v);
            a1h[pA * TST + c0] = hb; a1l[pA * TST + c0] = f2bf(v - bf2f(hb));
            v = fmaxf(u01[r], 0.f); hb = f2bf(v);
            a1h[pA * TST + c1] = hb; a1l[pA * TST + c1] = f2bf(v - bf2f(hb));
            v = fmaxf(u10[r], 0.f); hb = f2bf(v);
            a1h[pB * TST + c0] = hb; a1l[pB * TST + c0] = f2bf(v - bf2f(hb));
            v = fmaxf(u11[r], 0.f); hb = f2bf(v);
            a1h[pB * TST + c1] = hb; a1l[pB * TST + c1] = f2bf(v - bf2f(hb));
        }
        gatem[blockIdx.x * 256 + t] = (unsigned short)mk;
    }
    __syncthreads();

    // Phase B: filt = a1 @ W2 via MFMA (4 ksteps, split AhBh+AhBl+AlBh).
    {
        int wid = t >> 6, lane = t & 63;
        int lr = lane & 15, lg = lane >> 4;
        int c0 = (2 * wid + 0) * 16 + lr;
        int c1 = (2 * wid + 1) * 16 + lr;
        f32x4 acc00 = {0.f,0.f,0.f,0.f}, acc01 = {0.f,0.f,0.f,0.f};
        f32x4 acc10 = {0.f,0.f,0.f,0.f}, acc11 = {0.f,0.f,0.f,0.f};
#pragma unroll
        for (int ks = 0; ks < 4; ks++) {
            int kb = ks * 32 + lg * 8;
            short8v ah0 = *(const short8v*)(a1h + (lr     ) * TST + kb);
            short8v ah1 = *(const short8v*)(a1h + (16 + lr) * TST + kb);
            short8v al0 = *(const short8v*)(a1l + (lr     ) * TST + kb);
            short8v al1 = *(const short8v*)(a1l + (16 + lr) * TST + kb);
            short8v bh0 = *(const short8v*)(w2fh + c0 * FD + kb);
            short8v bh1 = *(const short8v*)(w2fh + c1 * FD + kb);
            short8v bl0 = *(const short8v*)(w2fl + c0 * FD + kb);
            short8v bl1 = *(const short8v*)(w2fl + c1 * FD + kb);
            acc00 = MFMA_B16(ah0, bh0, acc00, 0,0,0);
            acc01 = MFMA_B16(ah0, bh1, acc01, 0,0,0);
            acc10 = MFMA_B16(ah1, bh0, acc10, 0,0,0);
            acc11 = MFMA_B16(ah1, bh1, acc11, 0,0,0);
            acc00 = MFMA_B16(ah0, bl0, acc00, 0,0,0);
            acc01 = MFMA_B16(ah0, bl1, acc01, 0,0,0);
            acc10 = MFMA_B16(ah1, bl0, acc10, 0,0,0);
            acc11 = MFMA_B16(ah1, bl1, acc11, 0,0,0);
            acc00 = MFMA_B16(al0, bh0, acc00, 0,0,0);
            acc01 = MFMA_B16(al0, bh1, acc01, 0,0,0);
            acc10 = MFMA_B16(al1, bh0, acc10, 0,0,0);
            acc11 = MFMA_B16(al1, bh1, acc11, 0,0,0);
        }
#pragma unroll
        for (int r = 0; r < 4; r++) {
            int pA = lg * 4 + r, pB = 16 + lg * 4 + r;
            filt_s[pA * AST + c0] = acc00[r];
            filt_s[pA * AST + c1] = acc01[r];
            filt_s[pB * AST + c0] = acc10[r];
            filt_s[pB * AST + c1] = acc11[r];
        }
    }
    __syncthreads();

    // Phase C: m[i,c] += (filt[p][c]+b2[c]) * hv[p]; thread = (c, half)
    {
        int c = t & 127, ph = t >> 7;
        float b2c = b2[c];
        float r = 0.f;
        int p0 = ph * 16;
        int cur_i = pis[p0];
#pragma unroll
        for (int e = 0; e < 16; e++) {
            int p = p0 + e;
            int ip = pis[p];
            if (ip != cur_i) {
                atomicAdd(m + cur_i * FD + c, r);
                r = 0.f; cur_i = ip;
            }
            if (base + p < np)
                r += (filt_s[p * AST + c] + b2c) * hv[e];
        }
        atomicAdd(m + cur_i * FD + c, r);
    }
}

// ---------------------------------------------------------------- mbar (R20/R25)
// One block per atom: mbar_i = W3T @ (wout * gate(m_i @ W3)).
// R25: operand-swapped reads -> per-thread contiguous float4 streams.
__global__ __launch_bounds__(256) void mbar_kernel(
    const float* __restrict__ m, const float* __restrict__ W3,
    const float* __restrict__ W3T, const float* __restrict__ wout,
    float* __restrict__ mbar)
{
    __shared__ float mrow[FD];
    __shared__ float gb[FD];
    __shared__ float part[256];
    int i = blockIdx.x, t = threadIdx.x;
    if (t < FD) mrow[t] = m[i * FD + t];
    __syncthreads();
    int c = t & 127, hh = t >> 7;          // hh = 0/1 -> f half
    int f0 = hh * 64;
    float g = 0.f;
#pragma unroll 4
    for (int f4 = f0; f4 < f0 + 64; f4 += 4) {
        float4 w  = *(const float4*)(W3T + c * FD + f4);   // W3T[c][f]=W3[f][c]
        float4 mr = *(const float4*)(mrow + f4);
        g += mr.x*w.x + mr.y*w.y + mr.z*w.z + mr.w*w.w;
    }
    part[t] = g;
    __syncthreads();
    if (t < FD) gb[t] = (part[t] + part[t + 128] > 0.f) ? wout[t] : 0.f;
    __syncthreads();
    float mb = 0.f;
#pragma unroll 4
    for (int f4 = f0; f4 < f0 + 64; f4 += 4) {
        float4 w  = *(const float4*)(W3 + c * FD + f4);    // W3[c][f]=W3T[f][c]
        float4 gv = *(const float4*)(gb + f4);
        mb += gv.x*w.x + gv.y*w.y + gv.z*w.z + gv.w*w.w;
    }
    part[t] = mb;
    __syncthreads();
    if (t < FD) mbar[i * FD + t] = part[t] + part[t + 128];
}

// ---------------------------------------------------------------- bwd (PPBW=32, MFMA)
// R25: stage(crbf only) + ts-fill + gate-mask load -> barrier -> gef MFMA
// (12, in registers) -> GEMM MFMA -> in-reg fold + shuffle reduce -> scatter.
__global__ __launch_bounds__(256) void bwd_kernel(
    const unsigned short* __restrict__ w1fh, const unsigned short* __restrict__ w1fl,
    const unsigned short* __restrict__ w2bh, const unsigned short* __restrict__ w2bl,
    const float* __restrict__ h, const float* __restrict__ mbar,
    const unsigned short* __restrict__ gatem,
    const int* __restrict__ pair_i, const int* __restrict__ pair_j,
    const float* __restrict__ pair_d, const float* __restrict__ pair_dx,
    const float* __restrict__ pair_dy, const float* __restrict__ pair_dz,
    const int* __restrict__ npairs_ctr, float* __restrict__ f_acc)
{
    __shared__ __align__(16) unsigned short crbf_h[PPBW * RSTU];  // 2560 B
    __shared__ __align__(16) unsigned short crbf_l[PPBW * RSTU];  // 2560 B
    __shared__ __align__(16) unsigned short ts_h[PPBW * TST];     // 8704 B
    __shared__ __align__(16) unsigned short ts_l[PPBW * TST];     // 8704 B
    __shared__ float sred[4 * PPBW];                              // 512 B
    __shared__ int   pis[PPBW], pjs[PPBW];                        // 256 B (~23.3 KB)
    int t = threadIdx.x;
    int base = blockIdx.x * PPBW;
    int np = npairs_ctr[0];
    if (base >= np) return;

    if (t < PPBW) {
        int p = base + t; bool ok = p < np;
        pis[t] = ok ? pair_i[p] : 0;
        pjs[t] = ok ? pair_j[p] : 0;
    }
    unsigned int mk = gatem[blockIdx.x * 256 + t];   // fwd-stored relu gates
    for (int idx = t; idx < PPBW * NRBF; idx += 256) {
        int p = idx >> 5, k = idx & 31;
        int gp = base + p;
        float d = (gp < np) ? pair_d[gp] : 1.0f;
        float u = d - CSTEP * (float)k;
        float r = __expf(-GAMMA_ * u * u);
        float cd = -2.f * GAMMA_ * u * r;
        unsigned short hc = f2bf(cd);
        crbf_h[p * RSTU + k] = hc;
        crbf_l[p * RSTU + k] = f2bf(cd - bf2f(hc));
    }
    // scatter-phase pair data prefetch (threads 0..31)
    float pd = 1.f, pdx = 0.f, pdy = 0.f, pdz = 0.f;
    if (t < PPBW && base + t < np) {
        pd  = pair_d [base + t];
        pdx = pair_dx[base + t];
        pdy = pair_dy[base + t];
        pdz = pair_dz[base + t];
    }
    // ts-fill: ts[p][c] = mbar[i_p][c] * h[j_p][c] -> bf16 hi/lo in LDS.
    // pis/pjs written by threads t<32 with no barrier yet: recompute indices
    // from global to stay race-free.
    for (int idx = t; idx < PPBW * 32; idx += 256) {
        int p = idx >> 5, c4g = (idx & 31) * 4;
        int gp = base + p;
        int ip = (gp < np) ? pair_i[gp] : 0;
        int jp = (gp < np) ? pair_j[gp] : 0;
        float4 mb4 = *(const float4*)(mbar + ip * FD + c4g);
        float4 hj4 = *(const float4*)(h    + jp * FD + c4g);
        float v0 = mb4.x*hj4.x, v1 = mb4.y*hj4.y, v2 = mb4.z*hj4.z, v3 = mb4.w*hj4.w;
        ushort4 hv, lv;
        hv.x = f2bf(v0); lv.x = f2bf(v0 - bf2f(hv.x));
        hv.y = f2bf(v1); lv.y = f2bf(v1 - bf2f(hv.y));
        hv.z = f2bf(v2); lv.z = f2bf(v2 - bf2f(hv.z));
        hv.w = f2bf(v3); lv.w = f2bf(v3 - bf2f(hv.w));
        *(ushort4*)(ts_h + p * TST + c4g) = hv;
        *(ushort4*)(ts_l + p * TST + c4g) = lv;
    }
    __syncthreads();                       // crbf + ts + pis/pjs ready

    {
        int wid = t >> 6, lane = t & 63;
        int lr = lane & 15, lg = lane >> 4;
        int c0 = (2 * wid + 0) * 16 + lr;
        int c1 = (2 * wid + 1) * 16 + lr;

        // gef (12 MFMA, in registers): ef = crbf@W1 split; gate via mask.
        f32x4 e00 = {0.f,0.f,0.f,0.f}, e01 = {0.f,0.f,0.f,0.f};
        f32x4 e10 = {0.f,0.f,0.f,0.f}, e11 = {0.f,0.f,0.f,0.f};
        {
            short8v ch0 = *(const short8v*)(crbf_h + lr * RSTU + lg * 8);
            short8v ch1 = *(const short8v*)(crbf_h + (16+lr) * RSTU + lg * 8);
            short8v cl0 = *(const short8v*)(crbf_l + lr * RSTU + lg * 8);
            short8v cl1 = *(const short8v*)(crbf_l + (16+lr) * RSTU + lg * 8);
            short8v bh0 = *(const short8v*)(w1fh + c0 * NRBF + lg * 8);
            short8v bh1 = *(const short8v*)(w1fh + c1 * NRBF + lg * 8);
            short8v bl0 = *(const short8v*)(w1fl + c0 * NRBF + lg * 8);
            short8v bl1 = *(const short8v*)(w1fl + c1 * NRBF + lg * 8);
            e00 = MFMA_B16(ch0, bh0, e00, 0,0,0); e01 = MFMA_B16(ch0, bh1, e01, 0,0,0);
            e10 = MFMA_B16(ch1, bh0, e10, 0,0,0); e11 = MFMA_B16(ch1, bh1, e11, 0,0,0);
            e00 = MFMA_B16(ch0, bl0, e00, 0,0,0); e01 = MFMA_B16(ch0, bl1, e01, 0,0,0);
            e10 = MFMA_B16(ch1, bl0, e10, 0,0,0); e11 = MFMA_B16(ch1, bl1, e11, 0,0,0);
            e00 = MFMA_B16(cl0, bh0, e00, 0,0,0); e01 = MFMA_B16(cl0, bh1, e01, 0,0,0);
            e10 = MFMA_B16(cl1, bh0, e10, 0,0,0); e11 = MFMA_B16(cl1, bh1, e11, 0,0,0);
        }
#pragma unroll
        for (int r = 0; r < 4; r++) {
            e00[r] = (mk & (1u <<  r      )) ? e00[r] : 0.f;
            e01[r] = (mk & (1u << (4 + r))) ? e01[r] : 0.f;
            e10[r] = (mk & (1u << (8 + r))) ? e10[r] : 0.f;
            e11[r] = (mk & (1u << (12 + r))) ? e11[r] : 0.f;
        }

        // GEMM: du1 = ts @ W2T (B[k][c']=W2[c'][k] from native-layout w2b).
        f32x4 acc00 = {0.f,0.f,0.f,0.f}, acc01 = {0.f,0.f,0.f,0.f};
        f32x4 acc10 = {0.f,0.f,0.f,0.f}, acc11 = {0.f,0.f,0.f,0.f};
#pragma unroll
        for (int ks = 0; ks < 4; ks++) {
            int kb = ks * 32 + lg * 8;
            short8v ah0 = *(const short8v*)(ts_h + (lr     ) * TST + kb);
            short8v ah1 = *(const short8v*)(ts_h + (16 + lr) * TST + kb);
            short8v al0 = *(const short8v*)(ts_l + (lr     ) * TST + kb);
            short8v al1 = *(const short8v*)(ts_l + (16 + lr) * TST + kb);
            short8v bh0 = *(const short8v*)(w2bh + c0 * FD + kb);
            short8v bh1 = *(const short8v*)(w2bh + c1 * FD + kb);
            short8v bl0 = *(const short8v*)(w2bl + c0 * FD + kb);
            short8v bl1 = *(const short8v*)(w2bl + c1 * FD + kb);
            acc00 = MFMA_B16(ah0, bh0, acc00, 0,0,0);
            acc01 = MFMA_B16(ah0, bh1, acc01, 0,0,0);
            acc10 = MFMA_B16(ah1, bh0, acc10, 0,0,0);
            acc11 = MFMA_B16(ah1, bh1, acc11, 0,0,0);
            acc00 = MFMA_B16(ah0, bl0, acc00, 0,0,0);
            acc01 = MFMA_B16(ah0, bl1, acc01, 0,0,0);
            acc10 = MFMA_B16(ah1, bl0, acc10, 0,0,0);
            acc11 = MFMA_B16(ah1, bl1, acc11, 0,0,0);
            acc00 = MFMA_B16(al0, bh0, acc00, 0,0,0);
            acc01 = MFMA_B16(al0, bh1, acc01, 0,0,0);
            acc10 = MFMA_B16(al1, bh0, acc10, 0,0,0);
            acc11 = MFMA_B16(al1, bh1, acc11, 0,0,0);
        }

        // Epilogue: fold in-register gef, 16-lane shuffle reduce over cols.
        float part[8];
#pragma unroll
        for (int r = 0; r < 4; r++) {
            part[r]     = acc00[r] * e00[r] + acc01[r] * e01[r];
            part[4 + r] = acc10[r] * e10[r] + acc11[r] * e11[r];
        }
#pragma unroll
        for (int mask = 1; mask < 16; mask <<= 1) {
#pragma unroll
            for (int e = 0; e < 8; e++) part[e] += __shfl_xor(part[e], mask, 64);
        }
        if (lr == 0) {
#pragma unroll
            for (int r = 0; r < 4; r++) {
                sred[wid * PPBW + lg * 4 + r]      = part[r];
                sred[wid * PPBW + 16 + lg * 4 + r] = part[4 + r];
            }
        }
    }
    __syncthreads();

    // Final per-pair scatter (32 pairs by threads 0..31; pair data prefetched)
    if (t < PPBW) {
        int gp = base + t;
        if (gp < np) {
            float s = sred[t] + sred[PPBW + t] + sred[2*PPBW + t] + sred[3*PPBW + t];
            int ii = pis[t], jj = pjs[t];
            float coef = s / pd;
            float fx = coef * pdx;
            float fy = coef * pdy;
            float fz = coef * pdz;
            atomicAdd(f_acc + ii*3 + 0, -fx);
            atomicAdd(f_acc + ii*3 + 1, -fy);
            atomicAdd(f_acc + ii*3 + 2, -fz);
            atomicAdd(f_acc + jj*3 + 0, fx);
            atomicAdd(f_acc + jj*3 + 1, fy);
            atomicAdd(f_acc + jj*3 + 2, fz);
        }
    }
}

// ---------------------------------------------------------------- finalize
__global__ __launch_bounds__(256) void fin_kernel(
    const float* __restrict__ v, const float* __restrict__ mass,
    const float* __restrict__ p_eta, const float* __restrict__ f_acc,
    float* __restrict__ out)
{
    __shared__ float red[256];
    int t = threadIdx.x;
    float ke = 0.f;
    float c = p_eta[0] / Q0_F;
    for (int idx = t; idx < 3 * N_ATOMS; idx += 256) {
        int a = idx / 3;
        float vv = v[idx], mi = mass[a];
        out[DVDT_OFF + idx] = (f_acc[idx] - c * vv * mi) / mi;
        out[V_OFF + idx] = vv;
        ke += 0.5f * mi * vv * vv;
    }
    red[t] = ke;
    __syncthreads();
    for (int s = 128; s > 0; s >>= 1) {
        if (t < s) red[t] += red[t + s];
        __syncthreads();
    }
    if (t == 0) {
        float k0 = red[0];
        float e0 = p_eta[0], e1 = p_eta[1], e2 = p_eta[2], e3 = p_eta[3];
        out[PETA_OFF + 0] = 2.f * (k0 - TARGET_KE) - e0 * e1 / QI_F;
        out[PETA_OFF + 1] = e0 * e0 / Q0_F - KT_F - e1 * e2 / QI_F;
        out[PETA_OFF + 2] = e1 * e1 / QI_F - KT_F - e2 * e3 / QI_F;
        out[PETA_OFF + 3] = e2 * e2 / QI_F - KT_F;
    }
}

// ---------------------------------------------------------------- launch
extern "C" void kernel_launch(void* const* d_in, const int* in_sizes, int n_in,
                              void* d_out, int out_size, void* d_ws, size_t ws_size,
                              hipStream_t stream)
{
    const float* v     = (const float*)d_in[0];
    const float* q     = (const float*)d_in[1];
    const float* p_eta = (const float*)d_in[2];
    const float* mass  = (const float*)d_in[3];
    const float* embed = (const float*)d_in[4];
    const float* W1    = (const float*)d_in[5];
    const float* b1    = (const float*)d_in[6];
    const float* W2    = (const float*)d_in[7];
    const float* b2    = (const float*)d_in[8];
    const float* W3    = (const float*)d_in[9];
    const float* wout  = (const float*)d_in[10];
    const int*   z     = (const int*)d_in[11];
    float* out = (float*)d_out;

    float* h     = (float*)d_ws;
    float* W2T_unused = h + N_ATOMS * FD;        // slot kept (layout stability)
    float* W3T   = W2T_unused + FD * FD;
    float* m     = W3T + FD * FD;
    float* f_acc = m + N_ATOMS * FD;
    float* pair_d  = f_acc + 3 * N_ATOMS;
    float* pair_dx = pair_d + N_ATOMS * MAXN;
    float* pair_dy = pair_dx + N_ATOMS * MAXN;
    float* pair_dz = pair_dy + N_ATOMS * MAXN;
    int* pair_i = (int*)(pair_dz + N_ATOMS * MAXN);
    int* pair_j = pair_i + N_ATOMS * MAXN;
    int* npairs_ctr = pair_j + N_ATOMS * MAXN;
    float* mbar  = (float*)(npairs_ctr + 64);     // 64-int pad for alignment
    unsigned short* w2bh = (unsigned short*)(mbar + N_ATOMS * FD);
    unsigned short* w2bl = w2bh + FD * FD;
    unsigned short* w2fh = w2bl + FD * FD;
    unsigned short* w2fl = w2fh + FD * FD;
    unsigned short* w1fh = w2fl + FD * FD;
    unsigned short* w1fl = w1fh + NRBF * FD;
    unsigned short* gatem = w1fl + NRBF * FD;     // FTILES*256 gate masks

    hipMemsetAsync(npairs_ctr, 0, sizeof(int), stream);

    prep_kernel<<<N_ATOMS, 256, 0, stream>>>(q, z, embed, W1, W2, W3, h, W3T,
                                             w1fh, w1fl, w2fh, w2fl, w2bh, w2bl,
                                             pair_i, pair_j, pair_d,
                                             pair_dx, pair_dy, pair_dz,
                                             npairs_ctr, m, f_acc);
    fwd_kernel<<<FTILES, 256, 0, stream>>>(w1fh, w1fl, b1, w2fh, w2fl, b2, h,
                                           pair_i, pair_j, pair_d, npairs_ctr,
                                           m, gatem);
    mbar_kernel<<<N_ATOMS, 256, 0, stream>>>(m, W3, W3T, wout, mbar);
    bwd_kernel<<<BTILES, 256, 0, stream>>>(w1fh, w1fl, w2bh, w2bl, h, mbar,
                                           gatem,
                                           pair_i, pair_j, pair_d, pair_dx,
                                           pair_dy, pair_dz, npairs_ctr, f_acc);
    fin_kernel<<<1, 256, 0, stream>>>(v, mass, p_eta, f_acc, out);
}